// Round 1
// baseline (451.203 us; speedup 1.0000x reference)
//
#include <hip/hip_runtime.h>
#include <math.h>

typedef __bf16 bf16x8 __attribute__((ext_vector_type(8)));
typedef float  f32x4  __attribute__((ext_vector_type(4)));

// problem constants
// N=2, Q=1600(=40*40), K=100, C=256, heads=8, d=32, keys padded to 112 (7 mtiles)

// ---- workspace layout (float offsets) ----
#define WS_QE   0u         // [3200][256] f32 query sin/cos table
#define WS_KE   819200u    // [200][256]  f32 key sin/cos table
#define WS_QH   870400u    // [3200][256] f32 scaled q projection
#define WS_KH   1689600u   // [200][256]  f32 k projection
#define WS_VH   1740800u   // [200][256]  f32 v projection
#define WS_OWT  1792000u   // [256][256]  f32 out_proj_w transposed [j][c]
#define WS_EWT  1857536u   // [258][256]  f32 embed_w transposed [j][c]
#define WS_IPWT 1923584u   // [256][768]  f32 in_proj_w transposed [j][o]
#define WS_BF16 2120192u   // bf16 area: w1b [256][256], then w2pb [16][256]
// total ~8.62 MB

// ---------------------------------------------------------------------------
// prep: bf16 casts + weight transposes
__global__ __launch_bounds__(256) void prep_kernel(
    const float* __restrict__ pos_w1, const float* __restrict__ pos_w2,
    const float* __restrict__ out_w, const float* __restrict__ embed_w,
    const float* __restrict__ ipw, float* __restrict__ ws)
{
  int idx = blockIdx.x * 256 + threadIdx.x;
  __bf16* w1b  = (__bf16*)(ws + WS_BF16);
  __bf16* w2pb = w1b + 65536;
  if (idx < 65536) {
    w1b[idx] = (__bf16)pos_w1[idx];
  } else if (idx < 65536 + 4096) {
    int i = idx - 65536;
    int r = i >> 8;
    w2pb[i] = (r < 8) ? (__bf16)pos_w2[i] : (__bf16)0.0f;
  } else if (idx < 65536 + 4096 + 65536) {
    int i = idx - (65536 + 4096);
    int j = i >> 8, c = i & 255;
    ws[WS_OWT + i] = out_w[c * 256 + j];
  } else if (idx < 65536 + 4096 + 65536 + 66048) {
    int i = idx - (65536 + 4096 + 65536);
    int j = i >> 8, c = i & 255;
    ws[WS_EWT + i] = embed_w[c * 258 + j];
  } else if (idx < 65536 + 4096 + 65536 + 66048 + 196608) {
    int i = idx - (65536 + 4096 + 65536 + 66048);
    int j = i / 768, o = i % 768;
    ws[WS_IPWT + i] = ipw[o * 256 + j];
  }
}

// ---------------------------------------------------------------------------
// sin/cos tables: slot 2i -> sin(p/t_i), 2i+1 -> cos(p/t_i), t_i = 10000^(i/64)
// rows 0..3199: queries; rows 3200..3399: keys
__global__ __launch_bounds__(256) void tables_kernel(
    const float* __restrict__ qpos, const float* __restrict__ kpos,
    float* __restrict__ ws)
{
  int r = blockIdx.x;
  int t = threadIdx.x;
  int c = t >> 7;          // which coordinate (0/1)
  int i = (t & 127) >> 1;  // frequency index
  float p; float* out;
  if (r < 3200) { p = qpos[r * 2 + c]; out = ws + WS_QE + (unsigned)r * 256u; }
  else { int rk = r - 3200; p = kpos[rk * 2 + c]; out = ws + WS_KE + (unsigned)rk * 256u; }
  float inv = exp2f((float)i * (-13.287712379549449f / 64.0f)); // 10000^(-i/64)
  float v = p * inv;
  out[t] = (t & 1) ? cosf(v) : sinf(v);
}

// ---------------------------------------------------------------------------
// q/k/v projections. blocks 0..399: 8 query rows each; 400..407: 25 key rows (k+v)
__global__ __launch_bounds__(256) void proj_kernel(
    const float* __restrict__ qfeat, const float* __restrict__ kfeat,
    const float* __restrict__ ipb, float* __restrict__ ws)
{
  __shared__ float x[25 * 256];
  const float* ipwT = ws + WS_IPWT;
  int b = blockIdx.x, t = threadIdx.x;
  if (b < 400) {
    int r0 = b * 8;
    for (int i = t; i < 8 * 256; i += 256) x[i] = qfeat[(unsigned)r0 * 256u + i];
    __syncthreads();
    float acc[8];
    float bq = ipb[t];
#pragma unroll
    for (int rr = 0; rr < 8; rr++) acc[rr] = bq;
    for (int j = 0; j < 256; j++) {
      float w = ipwT[j * 768 + t];
#pragma unroll
      for (int rr = 0; rr < 8; rr++) acc[rr] = fmaf(x[rr * 256 + j], w, acc[rr]);
    }
#pragma unroll
    for (int rr = 0; rr < 8; rr++)
      ws[WS_QH + (unsigned)(r0 + rr) * 256u + t] = acc[rr] * 0.17677669529663687f; // *32^-0.5
  } else {
    int b2 = b - 400;
    int n = b2 >> 2, tile = b2 & 3;
    int r0 = n * 100 + tile * 25;
    for (int i = t; i < 25 * 256; i += 256) x[i] = kfeat[(unsigned)r0 * 256u + i];
    __syncthreads();
    float acck[25], accv[25];
    float bk = ipb[256 + t], bv = ipb[512 + t];
#pragma unroll
    for (int rr = 0; rr < 25; rr++) { acck[rr] = bk; accv[rr] = bv; }
    for (int j = 0; j < 256; j++) {
      float wk = ipwT[j * 768 + 256 + t];
      float wv = ipwT[j * 768 + 512 + t];
#pragma unroll
      for (int rr = 0; rr < 25; rr++) {
        float xv = x[rr * 256 + j];
        acck[rr] = fmaf(xv, wk, acck[rr]);
        accv[rr] = fmaf(xv, wv, accv[rr]);
      }
    }
#pragma unroll
    for (int rr = 0; rr < 25; rr++) {
      ws[WS_KH + (unsigned)(r0 + rr) * 256u + t] = acck[rr];
      ws[WS_VH + (unsigned)(r0 + rr) * 256u + t] = accv[rr];
    }
  }
}

// ---------------------------------------------------------------------------
// fused per-query kernel: pe-gen -> MFMA hid -> MFMA bias -> attn -> epilogues
// LDS map (bytes):
//   [0..57344)   phase A: peA frags (first 7168); phase B: hidA bf16 [7][8][64][8]
//                phase C: scores f32[8][112] @0, ctx f32[256] @3584, cat f32[258] @4608
//   [57344..60928)  bias_s f32 [112][8]
//   [60928..61952)  qe_s f32[256]
//   [61952..62976)  qh_s f32[256]
//   [62976..63424)  aw_s f32[112]
__global__ __launch_bounds__(256, 2) void big_kernel(
    const float* __restrict__ qfeat, const float* __restrict__ qpos,
    const float* __restrict__ kpos,
    const float* __restrict__ pos_b1, const float* __restrict__ pos_b2,
    const float* __restrict__ out_b, const float* __restrict__ embed_b,
    const float* __restrict__ ptw,
    const float* __restrict__ ws, float* __restrict__ out)
{
  __shared__ __align__(16) char smem[63424];
  float* qe_s   = (float*)(smem + 60928);
  float* qh_s   = (float*)(smem + 61952);
  float* aw_s   = (float*)(smem + 62976);
  float* bias_s = (float*)(smem + 57344);
  bf16x8* peA   = (bf16x8*)smem;
  __bf16* hidA  = (__bf16*)smem;

  int bid = blockIdx.x;
  int n = bid / 1600;
  int t = threadIdx.x;
  int lane = t & 63, w = t >> 6;

  const float* QE = ws + WS_QE;
  const float* KE = ws + WS_KE;
  const float* qh = ws + WS_QH;
  const float* kh = ws + WS_KH;
  const float* vh = ws + WS_VH;
  const __bf16* w1b  = (const __bf16*)(ws + WS_BF16);
  const __bf16* w2pb = w1b + 65536;

  qe_s[t] = QE[(unsigned)bid * 256u + t];
  qh_s[t] = qh[(unsigned)bid * 256u + t];
  __syncthreads();

  f32x4 zero4; zero4[0] = 0.f; zero4[1] = 0.f; zero4[2] = 0.f; zero4[3] = 0.f;
  f32x4 acc[4][7];
#pragma unroll
  for (int nt = 0; nt < 4; nt++)
#pragma unroll
    for (int mt = 0; mt < 7; mt++) acc[nt][mt] = zero4;

  const float4* qe4 = (const float4*)qe_s;

  for (int kc = 0; kc < 8; kc++) {
    // ---- generate pe A-fragments for this kchunk (angle-difference identity)
    for (int s = t; s < 448; s += 256) {
      int mt = s >> 6, l = s & 63;
      int key = mt * 16 + (l & 15);
      int k0 = kc * 32 + ((l >> 4) << 3);
      bf16x8 fr;
      if (key < 100) {
        const float* kep = KE + ((unsigned)(n * 100 + key) * 256u + k0);
        float4 ka = *(const float4*)kep;
        float4 kb = *(const float4*)(kep + 4);
        float4 qa = qe4[k0 >> 2];
        float4 qb = qe4[(k0 >> 2) + 1];
        // sin(a-b) = sa*cb - ca*sb ; cos(a-b) = ca*cb + sa*sb
        float p0 = ka.x * qa.y - ka.y * qa.x;
        float p1 = ka.y * qa.y + ka.x * qa.x;
        float p2 = ka.z * qa.w - ka.w * qa.z;
        float p3 = ka.w * qa.w + ka.z * qa.z;
        float p4 = kb.x * qb.y - kb.y * qb.x;
        float p5 = kb.y * qb.y + kb.x * qb.x;
        float p6 = kb.z * qb.w - kb.w * qb.z;
        float p7 = kb.w * qb.w + kb.z * qb.z;
        fr[0] = (__bf16)p0; fr[1] = (__bf16)p1; fr[2] = (__bf16)p2; fr[3] = (__bf16)p3;
        fr[4] = (__bf16)p4; fr[5] = (__bf16)p5; fr[6] = (__bf16)p6; fr[7] = (__bf16)p7;
      } else {
        fr[0] = (__bf16)0.f; fr[1] = (__bf16)0.f; fr[2] = (__bf16)0.f; fr[3] = (__bf16)0.f;
        fr[4] = (__bf16)0.f; fr[5] = (__bf16)0.f; fr[6] = (__bf16)0.f; fr[7] = (__bf16)0.f;
      }
      peA[s] = fr;
    }
    __syncthreads();
    // ---- MFMA: wave w owns ntiles 4w..4w+3
    bf16x8 afrag[7];
#pragma unroll
    for (int mt = 0; mt < 7; mt++) afrag[mt] = peA[mt * 64 + lane];
#pragma unroll
    for (int nt = 0; nt < 4; nt++) {
      int row = (w * 4 + nt) * 16 + (lane & 15);
      bf16x8 bfrag = *(const bf16x8*)(w1b + (unsigned)row * 256u + kc * 32 + ((lane >> 4) << 3));
#pragma unroll
      for (int mt = 0; mt < 7; mt++)
        acc[nt][mt] = __builtin_amdgcn_mfma_f32_16x16x32_bf16(afrag[mt], bfrag, acc[nt][mt], 0, 0, 0);
    }
    __syncthreads();
  }

  // ---- epilogue: +b1, relu, scatter into hidA (A-frag layout)
  {
    int mbase = (lane >> 4) * 4;
#pragma unroll
    for (int nt = 0; nt < 4; nt++) {
      int ncol = (w * 4 + nt) * 16 + (lane & 15);
      float b1v = pos_b1[ncol];
      int cc = ncol >> 5;
      int lane2base = (((ncol & 31) >> 3) << 4);
      int j2 = ncol & 7;
#pragma unroll
      for (int mt = 0; mt < 7; mt++) {
#pragma unroll
        for (int r = 0; r < 4; r++) {
          float v = fmaxf(acc[nt][mt][r] + b1v, 0.0f);
          hidA[(((mt * 8 + cc) * 64) + (lane2base | (mbase + r))) * 8 + j2] = (__bf16)v;
        }
      }
    }
  }
  __syncthreads();

  // ---- bias MFMA: biasT[m][h] = sum_c hid[m][c] * w2[h][c]
  {
    bf16x8* hidAv = (bf16x8*)smem;
#pragma unroll
    for (int ii = 0; ii < 2; ii++) {
      int mt = w + ii * 4;
      if (mt < 7) {
        f32x4 bacc = zero4;
#pragma unroll
        for (int cc = 0; cc < 8; cc++) {
          bf16x8 a2 = hidAv[(mt * 8 + cc) * 64 + lane];
          bf16x8 b2 = *(const bf16x8*)(w2pb + (unsigned)(lane & 15) * 256u + cc * 32 + ((lane >> 4) << 3));
          bacc = __builtin_amdgcn_mfma_f32_16x16x32_bf16(a2, b2, bacc, 0, 0, 0);
        }
        int h = lane & 15;
        if (h < 8) {
          float b2v = pos_b2[h];
#pragma unroll
          for (int r = 0; r < 4; r++) {
            int m = mt * 16 + (lane >> 4) * 4 + r;
            bias_s[m * 8 + h] = bacc[r] + b2v;
          }
        }
      }
    }
  }
  __syncthreads();

  // ---- phase C: scores -> softmax -> ctx / attn_w -> out_proj / cat_pos -> embed
  float* scores = (float*)smem;          // [8][112]
  float* ctx_s  = (float*)(smem + 3584); // [256]
  float* cat_s  = (float*)(smem + 4608); // [258]

  for (int p = t; p < 800; p += 256) {
    int h = p / 100, m = p % 100;
    const float4* kh4 = (const float4*)(kh + ((unsigned)(n * 100 + m) * 256u + h * 32));
    const float4* qh4 = (const float4*)(qh_s + h * 32);
    float s = bias_s[m * 8 + h];
#pragma unroll
    for (int dd = 0; dd < 8; dd++) {
      float4 kv = kh4[dd];
      float4 qv = qh4[dd];
      s += kv.x * qv.x + kv.y * qv.y + kv.z * qv.z + kv.w * qv.w;
    }
    scores[h * 112 + m] = s;
  }
  __syncthreads();

  if (t < 8) {
    float* row = scores + t * 112;
    float mx = -1e30f;
    for (int m = 0; m < 100; m++) mx = fmaxf(mx, row[m]);
    float sum = 0.f;
    for (int m = 0; m < 100; m++) { float e = __expf(row[m] - mx); row[m] = e; sum += e; }
    float inv = 1.0f / sum;
    for (int m = 0; m < 100; m++) row[m] *= inv;
  }
  __syncthreads();

  if (t < 100) {
    float s = 0.f;
#pragma unroll
    for (int h = 0; h < 8; h++) s += scores[h * 112 + t];
    aw_s[t] = s * 0.125f;
  }
  {
    int c = t, h = t >> 5;
    const float* vp = vh + ((unsigned)n * 100u * 256u + c);
    float s = 0.f;
    for (int m = 0; m < 100; m++) s = fmaf(scores[h * 112 + m], vp[m * 256], s);
    ctx_s[c] = s;
  }
  __syncthreads();

  if (t == 0) {
    float qp0 = qpos[bid * 2 + 0], qp1 = qpos[bid * 2 + 1];
    const float* kpp = kpos + (unsigned)n * 200u;
    float nr0 = 0.f, nr1 = 0.f;
    for (int m = 0; m < 100; m++) {
      float a = aw_s[m];
      nr0 = fmaf(a, kpp[m * 2 + 0] - qp0, nr0);
      nr1 = fmaf(a, kpp[m * 2 + 1] - qp1, nr1);
    }
    cat_s[256] = ptw[0] * nr0 + ptw[1] * nr1;
    cat_s[257] = ptw[2] * nr0 + ptw[3] * nr1;
  }
  {
    int c = t;
    const float* owt = ws + WS_OWT;
    float s = out_b[c];
    for (int j = 0; j < 256; j++) s = fmaf(ctx_s[j], owt[j * 256 + c], s);
    float f = qfeat[(unsigned)bid * 256u + c] + s;
    cat_s[c] = fmaxf(f, 0.f);
  }
  __syncthreads();
  {
    int c = t;
    const float* ewt = ws + WS_EWT;
    float s = embed_b[c];
    for (int j = 0; j < 258; j++) s = fmaf(cat_s[j], ewt[j * 256 + c], s);
    out[(unsigned)bid * 256u + c] = fmaxf(s, 0.f);
  }
}

// ---------------------------------------------------------------------------
extern "C" void kernel_launch(void* const* d_in, const int* in_sizes, int n_in,
                              void* d_out, int out_size, void* d_ws, size_t ws_size,
                              hipStream_t stream)
{
  const float* query_feature  = (const float*)d_in[0];
  const float* query_position = (const float*)d_in[1];
  const float* key_feature    = (const float*)d_in[2];
  const float* key_position   = (const float*)d_in[3];
  const float* in_proj_w      = (const float*)d_in[4];
  const float* in_proj_b      = (const float*)d_in[5];
  const float* out_proj_w     = (const float*)d_in[6];
  const float* out_proj_b     = (const float*)d_in[7];
  const float* pos_w1         = (const float*)d_in[8];
  const float* pos_b1         = (const float*)d_in[9];
  const float* pos_w2         = (const float*)d_in[10];
  const float* pos_b2         = (const float*)d_in[11];
  const float* pos_trans_w    = (const float*)d_in[12];
  const float* embed_w        = (const float*)d_in[13];
  const float* embed_b        = (const float*)d_in[14];
  float* ws  = (float*)d_ws;
  float* out = (float*)d_out;

  hipLaunchKernelGGL(prep_kernel, dim3(1554), dim3(256), 0, stream,
                     pos_w1, pos_w2, out_proj_w, embed_w, in_proj_w, ws);
  hipLaunchKernelGGL(tables_kernel, dim3(3400), dim3(256), 0, stream,
                     query_position, key_position, ws);
  hipLaunchKernelGGL(proj_kernel, dim3(408), dim3(256), 0, stream,
                     query_feature, key_feature, in_proj_b, ws);
  hipLaunchKernelGGL(big_kernel, dim3(3200), dim3(256), 0, stream,
                     query_feature, query_position, key_position,
                     pos_b1, pos_b2, out_proj_b, embed_b, pos_trans_w,
                     ws, out);
}

// Round 2
// 333.026 us; speedup vs baseline: 1.3549x; 1.3549x over previous
//
#include <hip/hip_runtime.h>
#include <math.h>

typedef __bf16 bf16x8 __attribute__((ext_vector_type(8)));
typedef __bf16 bf16x4 __attribute__((ext_vector_type(4)));
typedef float  f32x4  __attribute__((ext_vector_type(4)));

// N=2, Q=1600, K=100 (pad 112), C=256, h=8, d=32. Qb(bias)=2, Qb(attn)=4.

// ---- workspace layout (float offsets), total 2,098,176 floats = 8.39 MB ----
#define WS_KE    0u        // [200][256] f32 key sin/cos table
#define WS_KH    51200u    // [200][256] f32 k projection
#define WS_VH    102400u   // [200][256] f32 v projection
#define WS_EWP   153600u   // [256][260] f32 embed_w padded rows
#define WS_QHB   220160u   // bf16 [3200][256] scaled q projection (409600 f32-eq)
#define WS_BIASB 629760u   // bf16 [3200][112][8] rel-pos bias (1433600 f32-eq)
#define WS_W1B   2063360u  // bf16 [256][256] pos_w1
#define WS_W2PB  2096128u  // bf16 [16][256] pos_w2 padded

__device__ __forceinline__ float rdlane(float v, int l) {
  return __uint_as_float(__builtin_amdgcn_readlane(__float_as_uint(v), l));
}

// ---------------------------------------------------------------------------
// prep: KE tables + bf16 casts + embed_w pad + q/k/v projections (fused)
__global__ __launch_bounds__(256, 2) void prep_kernel(
    const float* __restrict__ qfeat, const float* __restrict__ kfeat,
    const float* __restrict__ kpos,
    const float* __restrict__ ipw, const float* __restrict__ ipb,
    const float* __restrict__ pos_w1, const float* __restrict__ pos_w2,
    const float* __restrict__ embed_w, float* __restrict__ ws)
{
  __shared__ float x[8 * 256];
  int bid = blockIdx.x, t = threadIdx.x;

  if (bid < 200) {
    // key sin/cos table: slot 2i -> sin(p/t_i), 2i+1 -> cos(p/t_i)
    int c = t >> 7, i = (t & 127) >> 1;
    float p = kpos[bid * 2 + c];
    float inv = exp2f((float)i * (-13.287712379549449f / 64.0f));
    float v = p * inv;
    ws[WS_KE + bid * 256 + t] = (t & 1) ? cosf(v) : sinf(v);
  } else if (bid < 264) {
    int idx = (bid - 200) * 1024 + t * 4;
    float4 v = *(const float4*)(pos_w1 + idx);
    bf16x4 o; o[0] = (__bf16)v.x; o[1] = (__bf16)v.y; o[2] = (__bf16)v.z; o[3] = (__bf16)v.w;
    *(bf16x4*)((__bf16*)(ws + WS_W1B) + idx) = o;
  } else if (bid == 264) {
    __bf16* w2pb = (__bf16*)(ws + WS_W2PB);
    for (int i = 0; i < 16; i++) {
      int idx = t * 16 + i;
      w2pb[idx] = (idx < 2048) ? (__bf16)pos_w2[idx] : (__bf16)0.0f;
    }
  } else if (bid < 297) {
    int r0 = (bid - 265) * 8;
    for (int rr = 0; rr < 8; rr++) {
      int r = r0 + rr;
      for (int j = t; j < 260; j += 256)
        ws[WS_EWP + r * 260 + j] = (j < 258) ? embed_w[r * 258 + j] : 0.0f;
    }
  } else if (bid < 697) {
    // proj-q: 8 rows, thread t = output col (wq row t)
    int r0 = (bid - 297) * 8;
    for (int i = t; i < 2048; i += 256) x[i] = qfeat[(unsigned)r0 * 256u + i];
    __syncthreads();
    float acc[8]; float bq = ipb[t];
#pragma unroll
    for (int rr = 0; rr < 8; rr++) acc[rr] = bq;
    const float* wrow = ipw + (unsigned)t * 256u;
    for (int j = 0; j < 256; j += 4) {
      float4 w4 = *(const float4*)(wrow + j);
#pragma unroll
      for (int rr = 0; rr < 8; rr++) {
        float4 x4 = *(const float4*)(x + rr * 256 + j);
        acc[rr] = fmaf(x4.x, w4.x, fmaf(x4.y, w4.y, fmaf(x4.z, w4.z, fmaf(x4.w, w4.w, acc[rr]))));
      }
    }
    __bf16* qhb = (__bf16*)(ws + WS_QHB);
#pragma unroll
    for (int rr = 0; rr < 8; rr++)
      qhb[(unsigned)(r0 + rr) * 256u + t] = (__bf16)(acc[rr] * 0.17677669529663687f);
  } else {
    // proj-kv: up to 7 rows, thread t handles k-col t and v-col t
    int b2 = bid - 697; int n = b2 >> 4, tile = b2 & 15;
    int r0l = tile * 7; int cnt = 100 - r0l; if (cnt > 7) cnt = 7; if (cnt <= 0) return;
    int r0 = n * 100 + r0l;
    for (int i = t; i < cnt * 256; i += 256) x[i] = kfeat[(unsigned)r0 * 256u + i];
    __syncthreads();
    float ak[7], av[7]; float bk = ipb[256 + t], bv = ipb[512 + t];
#pragma unroll
    for (int rr = 0; rr < 7; rr++) { ak[rr] = bk; av[rr] = bv; }
    const float* wkr = ipw + (unsigned)(256 + t) * 256u;
    const float* wvr = ipw + (unsigned)(512 + t) * 256u;
    for (int j = 0; j < 256; j += 4) {
      float4 wk4 = *(const float4*)(wkr + j);
      float4 wv4 = *(const float4*)(wvr + j);
#pragma unroll
      for (int rr = 0; rr < 7; rr++) {
        float4 x4 = *(const float4*)(x + rr * 256 + j);
        ak[rr] = fmaf(x4.x, wk4.x, fmaf(x4.y, wk4.y, fmaf(x4.z, wk4.z, fmaf(x4.w, wk4.w, ak[rr]))));
        av[rr] = fmaf(x4.x, wv4.x, fmaf(x4.y, wv4.y, fmaf(x4.z, wv4.z, fmaf(x4.w, wv4.w, av[rr]))));
      }
    }
    for (int rr = 0; rr < 7; rr++) {
      if (rr < cnt) {
        ws[WS_KH + (unsigned)(r0 + rr) * 256u + t] = ak[rr];
        ws[WS_VH + (unsigned)(r0 + rr) * 256u + t] = av[rr];
      }
    }
  }
}

// ---------------------------------------------------------------------------
// bias kernel: per block = 2 queries. pe-gen -> MFMA hid -> MFMA bias.
// 1024 threads = 16 waves. wave w: mh=w>>3 (mtile half), np=w&7 (ntile pair).
__global__ __launch_bounds__(1024) void bias_kernel(
    const float* __restrict__ qpos,
    const float* __restrict__ pos_b1, const float* __restrict__ pos_b2,
    float* __restrict__ ws)
{
  __shared__ __align__(16) char smem[57344];
  bf16x8* peA = (bf16x8*)smem;                 // [2 buf][896 frags]
  float* qe_s = (float*)(smem + 28672);        // [2][256]
  __bf16* hidA = (__bf16*)smem;                // epilogue reuse (57344 B)

  int bid = blockIdx.x;          // 0..1599 -> q rows bid*2, bid*2+1
  int n = bid / 800;
  int t = threadIdx.x;
  int lane = t & 63, w = t >> 6;
  int l15 = lane & 15, quad = lane >> 4;

  const float* KE = ws + WS_KE;
  const __bf16* w1b = (const __bf16*)(ws + WS_W1B);
  const __bf16* w2pb = (const __bf16*)(ws + WS_W2PB);
  __bf16* biasb = (__bf16*)(ws + WS_BIASB);

  if (t < 512) {
    int qq = t >> 8, u = t & 255;
    int c = u >> 7, i = (u & 127) >> 1;
    float p = qpos[(bid * 2 + qq) * 2 + c];
    float inv = exp2f((float)i * (-13.287712379549449f / 64.0f));
    float v = p * inv;
    qe_s[qq * 256 + u] = (u & 1) ? cosf(v) : sinf(v);
  }
  __syncthreads();

  auto gen = [&](int kc, int buf) {
    if (t < 896) {
      int qq = (t >= 448) ? 1 : 0;
      int s2 = t - qq * 448;
      int mtL = s2 >> 6, l = s2 & 63;
      int key = mtL * 16 + (l & 15);
      int k0 = kc * 32 + ((l >> 4) << 3);
      bf16x8 fr;
      if (key < 100) {
        const float* kep = KE + (n * 100 + key) * 256 + k0;
        float4 ka = *(const float4*)kep;
        float4 kb = *(const float4*)(kep + 4);
        const float4* qe4 = (const float4*)(qe_s + qq * 256);
        float4 qa = qe4[k0 >> 2];
        float4 qb = qe4[(k0 >> 2) + 1];
        float p0 = ka.x * qa.y - ka.y * qa.x;
        float p1 = ka.y * qa.y + ka.x * qa.x;
        float p2 = ka.z * qa.w - ka.w * qa.z;
        float p3 = ka.w * qa.w + ka.z * qa.z;
        float p4 = kb.x * qb.y - kb.y * qb.x;
        float p5 = kb.y * qb.y + kb.x * qb.x;
        float p6 = kb.z * qb.w - kb.w * qb.z;
        float p7 = kb.w * qb.w + kb.z * qb.z;
        fr[0] = (__bf16)p0; fr[1] = (__bf16)p1; fr[2] = (__bf16)p2; fr[3] = (__bf16)p3;
        fr[4] = (__bf16)p4; fr[5] = (__bf16)p5; fr[6] = (__bf16)p6; fr[7] = (__bf16)p7;
      } else {
        fr[0] = (__bf16)0.f; fr[1] = (__bf16)0.f; fr[2] = (__bf16)0.f; fr[3] = (__bf16)0.f;
        fr[4] = (__bf16)0.f; fr[5] = (__bf16)0.f; fr[6] = (__bf16)0.f; fr[7] = (__bf16)0.f;
      }
      peA[buf * 896 + t] = fr;
    }
  };

  int mh = w >> 3, np = w & 7;
  int ncol0 = (np * 2) * 16 + l15;
  int ncol1 = (np * 2 + 1) * 16 + l15;

  f32x4 zero4; zero4[0] = 0.f; zero4[1] = 0.f; zero4[2] = 0.f; zero4[3] = 0.f;
  f32x4 acc[2][7];
#pragma unroll
  for (int ntl = 0; ntl < 2; ntl++)
#pragma unroll
    for (int mt = 0; mt < 7; mt++) acc[ntl][mt] = zero4;

  gen(0, 0);
  __syncthreads();
  for (int kc = 0; kc < 8; kc++) {
    if (kc < 7) gen(kc + 1, (kc + 1) & 1);
    const __bf16* bp = w1b + kc * 32 + quad * 8;
    bf16x8 b0 = *(const bf16x8*)(bp + (unsigned)ncol0 * 256u);
    bf16x8 b1 = *(const bf16x8*)(bp + (unsigned)ncol1 * 256u);
    const bf16x8* pebuf = peA + (kc & 1) * 896;
#pragma unroll
    for (int mt = 0; mt < 7; mt++) {
      bf16x8 a = pebuf[(mh * 7 + mt) * 64 + lane];
      acc[0][mt] = __builtin_amdgcn_mfma_f32_16x16x32_bf16(a, b0, acc[0][mt], 0, 0, 0);
      acc[1][mt] = __builtin_amdgcn_mfma_f32_16x16x32_bf16(a, b1, acc[1][mt], 0, 0, 0);
    }
    __syncthreads();
  }

  // epilogue: two passes of 7 mtiles; scatter A-layout into LDS, MFMA vs w2
  float b1v0 = pos_b1[ncol0], b1v1 = pos_b1[ncol1];
  int cc = np;                      // ncol>>5, wave-uniform
  float b2v = pos_b2[l15 & 7];
  int j2 = l15 & 7;
#pragma unroll
  for (int pass = 0; pass < 2; pass++) {
    if (mh == pass) {
#pragma unroll
      for (int ntl = 0; ntl < 2; ntl++) {
        int ncl = ntl ? ncol1 : ncol0;
        float b1v = ntl ? b1v1 : b1v0;
        int lane2base = (((ncl & 31) >> 3) << 4);
#pragma unroll
        for (int mt = 0; mt < 7; mt++) {
#pragma unroll
          for (int r = 0; r < 4; r++) {
            float v = fmaxf(acc[ntl][mt][r] + b1v, 0.0f);
            hidA[(((mt * 8 + cc) * 64) + (lane2base | (quad * 4 + r))) * 8 + j2] = (__bf16)v;
          }
        }
      }
    }
    __syncthreads();
    if (w < 7) {
      int mtt = pass * 7 + w;
      f32x4 bacc = zero4;
#pragma unroll
      for (int c8 = 0; c8 < 8; c8++) {
        bf16x8 a2 = ((bf16x8*)smem)[(w * 8 + c8) * 64 + lane];
        bf16x8 b2 = *(const bf16x8*)(w2pb + (unsigned)l15 * 256u + c8 * 32 + quad * 8);
        bacc = __builtin_amdgcn_mfma_f32_16x16x32_bf16(a2, b2, bacc, 0, 0, 0);
      }
      if (l15 < 8) {
        int qq = (mtt >= 7) ? 1 : 0;
        int mk = mtt * 16 - qq * 112 + quad * 4;
        unsigned roww = (unsigned)(bid * 2 + qq) * 112u;
#pragma unroll
        for (int r = 0; r < 4; r++)
          biasb[(roww + mk + r) * 8u + l15] = (__bf16)(bacc[r] + b2v);
      }
    }
    __syncthreads();
  }
}

// ---------------------------------------------------------------------------
// attn kernel: per block = 4 queries. scores -> softmax -> ctx/aw -> out_proj
// -> cat_pos -> embed. 256 threads.
__global__ __launch_bounds__(256, 4) void attn_kernel(
    const float* __restrict__ qfeat, const float* __restrict__ qpos,
    const float* __restrict__ kpos,
    const float* __restrict__ out_w, const float* __restrict__ out_b,
    const float* __restrict__ embed_b, const float* __restrict__ ptw,
    const float* __restrict__ ws, float* __restrict__ out)
{
  __shared__ float qh_s[4 * 8 * 36];     // [q][h][36] padded
  __shared__ float attn_s[4 * 8 * 116];  // [q][h][116] padded
  __shared__ float ctx_s[4 * 264];
  __shared__ float cat_s[4 * 264];
  __shared__ float aw_s[4 * 104];

  int bid = blockIdx.x;
  int qg0 = bid * 4;
  int n = bid / 400;
  int t = threadIdx.x;

  const __bf16* qhb = (const __bf16*)(ws + WS_QHB);
  const __bf16* biasb = (const __bf16*)(ws + WS_BIASB);
  const float* kh = ws + WS_KH;
  const float* vh = ws + WS_VH;
  const float* ewp = ws + WS_EWP;

  for (int i = t; i < 1024; i += 256) {
    int q = i >> 8, c = i & 255;
    qh_s[(q * 8 + (c >> 5)) * 36 + (c & 31)] = (float)qhb[(unsigned)(qg0 + q) * 256u + c];
  }
  __syncthreads();

  // scores = qh.kh + bias  -> attn_s[q][h][k]
  for (int i = 0; i < 4; i++) {
    int p = t + i * 256;
    if (p < 800) {
      int k = p >> 3, h = p & 7;
      const float4* kf = (const float4*)(kh + (unsigned)(n * 100 + k) * 256u + h * 32);
      float4 kv[8];
#pragma unroll
      for (int dd = 0; dd < 8; dd++) kv[dd] = kf[dd];
#pragma unroll
      for (int q = 0; q < 4; q++) {
        const float4* qf = (const float4*)(qh_s + (q * 8 + h) * 36);
        float s = (float)biasb[((unsigned)(qg0 + q) * 112u + k) * 8u + h];
#pragma unroll
        for (int dd = 0; dd < 8; dd++) {
          float4 qv = qf[dd];
          s += kv[dd].x * qv.x + kv[dd].y * qv.y + kv[dd].z * qv.z + kv[dd].w * qv.w;
        }
        attn_s[(q * 8 + h) * 116 + k] = s;
      }
    }
  }
  __syncthreads();

  // softmax: 256 threads = 4q x 8h x 8 lanes-per-row
  {
    int q = t >> 6, h = (t >> 3) & 7, j = t & 7;
    float* row = attn_s + (q * 8 + h) * 116;
    float mx = -1e30f;
    for (int k = j; k < 100; k += 8) mx = fmaxf(mx, row[k]);
    mx = fmaxf(mx, __shfl_xor(mx, 1, 8));
    mx = fmaxf(mx, __shfl_xor(mx, 2, 8));
    mx = fmaxf(mx, __shfl_xor(mx, 4, 8));
    float sum = 0.f;
    for (int k = j; k < 100; k += 8) { float e = __expf(row[k] - mx); row[k] = e; sum += e; }
    sum += __shfl_xor(sum, 1, 8);
    sum += __shfl_xor(sum, 2, 8);
    sum += __shfl_xor(sum, 4, 8);
    float inv = 1.0f / sum;
    for (int k = j; k < 100; k += 8) row[k] *= inv;
  }
  __syncthreads();

  // aw = mean over heads
  for (int p = t; p < 416; p += 256) {
    int q = p / 104, k = p % 104;
    if (k < 100) {
      float s = 0.f;
#pragma unroll
      for (int h = 0; h < 8; h++) s += attn_s[(q * 8 + h) * 116 + k];
      aw_s[q * 104 + k] = s * 0.125f;
    }
  }
  // ctx[q][c] = sum_k attn[q][h(c)][k] * vh[k][c]
  {
    int c = t, h = c >> 5;
    float a0 = 0.f, a1 = 0.f, a2 = 0.f, a3 = 0.f;
    const float* vp = vh + (unsigned)(n * 100) * 256u + c;
    const float* r0 = attn_s + (0 * 8 + h) * 116;
    const float* r1 = attn_s + (1 * 8 + h) * 116;
    const float* r2 = attn_s + (2 * 8 + h) * 116;
    const float* r3 = attn_s + (3 * 8 + h) * 116;
#pragma unroll 4
    for (int k = 0; k < 100; k++) {
      float vv = vp[(unsigned)k * 256u];
      a0 = fmaf(r0[k], vv, a0);
      a1 = fmaf(r1[k], vv, a1);
      a2 = fmaf(r2[k], vv, a2);
      a3 = fmaf(r3[k], vv, a3);
    }
    ctx_s[0 * 264 + c] = a0; ctx_s[1 * 264 + c] = a1;
    ctx_s[2 * 264 + c] = a2; ctx_s[3 * 264 + c] = a3;
  }
  __syncthreads();

  // new_rel -> new_pos (cat extras), by threads 0..7 (one wave, shuffle combine)
  if (t < 8) {
    int q = t >> 1, cd = t & 1;
    float qp = qpos[(qg0 + q) * 2 + cd];
    float s = 0.f;
    for (int k = 0; k < 100; k++)
      s = fmaf(aw_s[q * 104 + k], kpos[(n * 100 + k) * 2 + cd] - qp, s);
    float so = __shfl_xor(s, 1, 2);
    if (cd == 0) cat_s[q * 264 + 256] = ptw[0] * s + ptw[1] * so;
    else         cat_s[q * 264 + 257] = ptw[2] * so + ptw[3] * s;
  }

  // out_proj: thread c owns out_w row c; ctx broadcast via readlane
  {
    int c = t, lane = t & 63;
    float ob = out_b[c];
    float acc0 = ob, acc1 = ob, acc2 = ob, acc3 = ob;
    const float* wr = out_w + (unsigned)c * 256u;
    for (int ch = 0; ch < 4; ch++) {
      float v0 = ctx_s[0 * 264 + ch * 64 + lane];
      float v1 = ctx_s[1 * 264 + ch * 64 + lane];
      float v2 = ctx_s[2 * 264 + ch * 64 + lane];
      float v3 = ctx_s[3 * 264 + ch * 64 + lane];
      const float* wp = wr + ch * 64;
#pragma unroll 4
      for (int j4 = 0; j4 < 16; j4++) {
        float4 w4 = *(const float4*)(wp + j4 * 4);
        int jb = j4 * 4;
        acc0 = fmaf(rdlane(v0, jb + 0), w4.x, acc0);
        acc1 = fmaf(rdlane(v1, jb + 0), w4.x, acc1);
        acc2 = fmaf(rdlane(v2, jb + 0), w4.x, acc2);
        acc3 = fmaf(rdlane(v3, jb + 0), w4.x, acc3);
        acc0 = fmaf(rdlane(v0, jb + 1), w4.y, acc0);
        acc1 = fmaf(rdlane(v1, jb + 1), w4.y, acc1);
        acc2 = fmaf(rdlane(v2, jb + 1), w4.y, acc2);
        acc3 = fmaf(rdlane(v3, jb + 1), w4.y, acc3);
        acc0 = fmaf(rdlane(v0, jb + 2), w4.z, acc0);
        acc1 = fmaf(rdlane(v1, jb + 2), w4.z, acc1);
        acc2 = fmaf(rdlane(v2, jb + 2), w4.z, acc2);
        acc3 = fmaf(rdlane(v3, jb + 2), w4.z, acc3);
        acc0 = fmaf(rdlane(v0, jb + 3), w4.w, acc0);
        acc1 = fmaf(rdlane(v1, jb + 3), w4.w, acc1);
        acc2 = fmaf(rdlane(v2, jb + 3), w4.w, acc2);
        acc3 = fmaf(rdlane(v3, jb + 3), w4.w, acc3);
      }
    }
    cat_s[0 * 264 + c] = fmaxf(qfeat[(unsigned)(qg0 + 0) * 256u + c] + acc0, 0.f);
    cat_s[1 * 264 + c] = fmaxf(qfeat[(unsigned)(qg0 + 1) * 256u + c] + acc1, 0.f);
    cat_s[2 * 264 + c] = fmaxf(qfeat[(unsigned)(qg0 + 2) * 256u + c] + acc2, 0.f);
    cat_s[3 * 264 + c] = fmaxf(qfeat[(unsigned)(qg0 + 3) * 256u + c] + acc3, 0.f);
  }
  __syncthreads();

  // embed: thread c owns ewp row c (stride 260, cols 256/257 = new_pos)
  {
    int c = t, lane = t & 63;
    float eb = embed_b[c];
    float acc0 = eb, acc1 = eb, acc2 = eb, acc3 = eb;
    const float* er = ewp + (unsigned)c * 260u;
    for (int ch = 0; ch < 4; ch++) {
      float v0 = cat_s[0 * 264 + ch * 64 + lane];
      float v1 = cat_s[1 * 264 + ch * 64 + lane];
      float v2 = cat_s[2 * 264 + ch * 64 + lane];
      float v3 = cat_s[3 * 264 + ch * 64 + lane];
      const float* wp = er + ch * 64;
#pragma unroll 4
      for (int j4 = 0; j4 < 16; j4++) {
        float4 w4 = *(const float4*)(wp + j4 * 4);
        int jb = j4 * 4;
        acc0 = fmaf(rdlane(v0, jb + 0), w4.x, acc0);
        acc1 = fmaf(rdlane(v1, jb + 0), w4.x, acc1);
        acc2 = fmaf(rdlane(v2, jb + 0), w4.x, acc2);
        acc3 = fmaf(rdlane(v3, jb + 0), w4.x, acc3);
        acc0 = fmaf(rdlane(v0, jb + 1), w4.y, acc0);
        acc1 = fmaf(rdlane(v1, jb + 1), w4.y, acc1);
        acc2 = fmaf(rdlane(v2, jb + 1), w4.y, acc2);
        acc3 = fmaf(rdlane(v3, jb + 1), w4.y, acc3);
        acc0 = fmaf(rdlane(v0, jb + 2), w4.z, acc0);
        acc1 = fmaf(rdlane(v1, jb + 2), w4.z, acc1);
        acc2 = fmaf(rdlane(v2, jb + 2), w4.z, acc2);
        acc3 = fmaf(rdlane(v3, jb + 2), w4.z, acc3);
        acc0 = fmaf(rdlane(v0, jb + 3), w4.w, acc0);
        acc1 = fmaf(rdlane(v1, jb + 3), w4.w, acc1);
        acc2 = fmaf(rdlane(v2, jb + 3), w4.w, acc2);
        acc3 = fmaf(rdlane(v3, jb + 3), w4.w, acc3);
      }
    }
    // cols 256/257 (new_pos); 258/259 pad are zero in EWP regardless
    float4 wt = *(const float4*)(er + 256);
    acc0 += cat_s[0 * 264 + 256] * wt.x + cat_s[0 * 264 + 257] * wt.y;
    acc1 += cat_s[1 * 264 + 256] * wt.x + cat_s[1 * 264 + 257] * wt.y;
    acc2 += cat_s[2 * 264 + 256] * wt.x + cat_s[2 * 264 + 257] * wt.y;
    acc3 += cat_s[3 * 264 + 256] * wt.x + cat_s[3 * 264 + 257] * wt.y;
    out[(unsigned)(qg0 + 0) * 256u + c] = fmaxf(acc0, 0.f);
    out[(unsigned)(qg0 + 1) * 256u + c] = fmaxf(acc1, 0.f);
    out[(unsigned)(qg0 + 2) * 256u + c] = fmaxf(acc2, 0.f);
    out[(unsigned)(qg0 + 3) * 256u + c] = fmaxf(acc3, 0.f);
  }
}

// ---------------------------------------------------------------------------
extern "C" void kernel_launch(void* const* d_in, const int* in_sizes, int n_in,
                              void* d_out, int out_size, void* d_ws, size_t ws_size,
                              hipStream_t stream)
{
  const float* query_feature  = (const float*)d_in[0];
  const float* query_position = (const float*)d_in[1];
  const float* key_feature    = (const float*)d_in[2];
  const float* key_position   = (const float*)d_in[3];
  const float* in_proj_w      = (const float*)d_in[4];
  const float* in_proj_b      = (const float*)d_in[5];
  const float* out_proj_w     = (const float*)d_in[6];
  const float* out_proj_b     = (const float*)d_in[7];
  const float* pos_w1         = (const float*)d_in[8];
  const float* pos_b1         = (const float*)d_in[9];
  const float* pos_w2         = (const float*)d_in[10];
  const float* pos_b2         = (const float*)d_in[11];
  const float* pos_trans_w    = (const float*)d_in[12];
  const float* embed_w        = (const float*)d_in[13];
  const float* embed_b        = (const float*)d_in[14];
  float* ws  = (float*)d_ws;
  float* out = (float*)d_out;

  hipLaunchKernelGGL(prep_kernel, dim3(729), dim3(256), 0, stream,
                     query_feature, key_feature, key_position,
                     in_proj_w, in_proj_b, pos_w1, pos_w2, embed_w, ws);
  hipLaunchKernelGGL(bias_kernel, dim3(1600), dim3(1024), 0, stream,
                     query_position, pos_b1, pos_b2, ws);
  hipLaunchKernelGGL(attn_kernel, dim3(800), dim3(256), 0, stream,
                     query_feature, query_position, key_position,
                     out_proj_w, out_proj_b, embed_b, pos_trans_w,
                     ws, out);
}

// Round 4
// 301.340 us; speedup vs baseline: 1.4973x; 1.1052x over previous
//
#include <hip/hip_runtime.h>
#include <math.h>

typedef __bf16 bf16x8 __attribute__((ext_vector_type(8)));
typedef __bf16 bf16x4 __attribute__((ext_vector_type(4)));
typedef float  f32x4  __attribute__((ext_vector_type(4)));

// N=2, Q=1600, K=100 (pad 112), C=256, h=8, d=32.
// bias: transposed MFMA GEMM, Qb=8/block. attn: Qb=4/block.

// ---- workspace layout (float offsets), total 2,073,376 f32 = 8.29 MB ----
// (round-3 bug: BIASB overlapped QHB; repacked with no overlap)
#define WS_KH    0u        // [200][256] f32 k projection                 -> 51200
#define WS_VH    51200u    // [200][256] f32 v projection                 -> 102400
#define WS_EWP   102400u   // [256][260] f32 embed_w padded rows          -> 168960
#define WS_QHB   168960u   // bf16 [3200][256] scaled q projection        -> 578560
#define WS_BIASB 578560u   // bf16 [3200][112][8] rel-pos bias            -> 2012160
#define WS_KEB   2012160u  // bf16 [200][264] key sin/cos table (pad 264) -> 2038560
#define WS_W1B   2038560u  // bf16 [256][256] pos_w1                      -> 2071328
#define WS_W2PB  2071328u  // bf16 [16][256] pos_w2 padded                -> 2073376

__device__ __forceinline__ float rdlane(float v, int l) {
  return __uint_as_float(__builtin_amdgcn_readlane(__float_as_uint(v), l));
}

// ---------------------------------------------------------------------------
// prep: keb table + bf16 casts + embed_w pad + q/k/v projections (fused)
__global__ __launch_bounds__(256, 2) void prep_kernel(
    const float* __restrict__ qfeat, const float* __restrict__ kfeat,
    const float* __restrict__ kpos,
    const float* __restrict__ ipw, const float* __restrict__ ipb,
    const float* __restrict__ pos_w1, const float* __restrict__ pos_w2,
    const float* __restrict__ embed_w, float* __restrict__ ws)
{
  __shared__ float x[8 * 256];
  int bid = blockIdx.x, t = threadIdx.x;

  if (bid < 50) {
    // key sin/cos table bf16, rows padded to 264: slot 2i->sin(p/t_i), 2i+1->cos
    int r = bid * 4 + (t >> 6);
    int u = t & 63;
    float p0 = kpos[r * 2 + 0], p1 = kpos[r * 2 + 1];
    __bf16* keb = (__bf16*)(ws + WS_KEB);
    bf16x4 o;
#pragma unroll
    for (int j = 0; j < 4; j++) {
      int col = u * 4 + j;
      int c = col >> 7, i = (col & 127) >> 1;
      float p = c ? p1 : p0;
      float inv = exp2f((float)i * (-13.287712379549449f / 64.0f));
      float v = p * inv;
      o[j] = (__bf16)((col & 1) ? __cosf(v) : __sinf(v));
    }
    *(bf16x4*)(keb + r * 264 + u * 4) = o;
  } else if (bid < 114) {
    int idx = (bid - 50) * 1024 + t * 4;
    float4 v = *(const float4*)(pos_w1 + idx);
    bf16x4 o; o[0] = (__bf16)v.x; o[1] = (__bf16)v.y; o[2] = (__bf16)v.z; o[3] = (__bf16)v.w;
    *(bf16x4*)((__bf16*)(ws + WS_W1B) + idx) = o;
  } else if (bid == 114) {
    __bf16* w2pb = (__bf16*)(ws + WS_W2PB);
    for (int i = 0; i < 16; i++) {
      int idx = t * 16 + i;
      w2pb[idx] = (idx < 2048) ? (__bf16)pos_w2[idx] : (__bf16)0.0f;
    }
  } else if (bid < 147) {
    int r0 = (bid - 115) * 8;
    for (int rr = 0; rr < 8; rr++) {
      int r = r0 + rr;
      for (int j = t; j < 260; j += 256)
        ws[WS_EWP + r * 260 + j] = (j < 258) ? embed_w[r * 258 + j] : 0.0f;
    }
  } else if (bid < 547) {
    // proj-q: 8 rows, thread t = output col (wq row t)
    int r0 = (bid - 147) * 8;
    for (int i = t; i < 2048; i += 256) x[i] = qfeat[(unsigned)r0 * 256u + i];
    __syncthreads();
    float acc[8]; float bq = ipb[t];
#pragma unroll
    for (int rr = 0; rr < 8; rr++) acc[rr] = bq;
    const float* wrow = ipw + (unsigned)t * 256u;
    for (int j = 0; j < 256; j += 4) {
      float4 w4 = *(const float4*)(wrow + j);
#pragma unroll
      for (int rr = 0; rr < 8; rr++) {
        float4 x4 = *(const float4*)(x + rr * 256 + j);
        acc[rr] = fmaf(x4.x, w4.x, fmaf(x4.y, w4.y, fmaf(x4.z, w4.z, fmaf(x4.w, w4.w, acc[rr]))));
      }
    }
    __bf16* qhb = (__bf16*)(ws + WS_QHB);
#pragma unroll
    for (int rr = 0; rr < 8; rr++)
      qhb[(unsigned)(r0 + rr) * 256u + t] = (__bf16)(acc[rr] * 0.17677669529663687f);
  } else {
    // proj-kv: up to 7 rows, thread t handles k-col t and v-col t
    int b2 = bid - 547; int n = b2 >> 4, tile = b2 & 15;
    int r0l = tile * 7; int cnt = 100 - r0l; if (cnt > 7) cnt = 7; if (cnt <= 0) return;
    int r0 = n * 100 + r0l;
    for (int i = t; i < cnt * 256; i += 256) x[i] = kfeat[(unsigned)r0 * 256u + i];
    __syncthreads();
    float ak[7], av[7]; float bk = ipb[256 + t], bv = ipb[512 + t];
#pragma unroll
    for (int rr = 0; rr < 7; rr++) { ak[rr] = bk; av[rr] = bv; }
    const float* wkr = ipw + (unsigned)(256 + t) * 256u;
    const float* wvr = ipw + (unsigned)(512 + t) * 256u;
    for (int j = 0; j < 256; j += 4) {
      float4 wk4 = *(const float4*)(wkr + j);
      float4 wv4 = *(const float4*)(wvr + j);
#pragma unroll
      for (int rr = 0; rr < 7; rr++) {
        float4 x4 = *(const float4*)(x + rr * 256 + j);
        ak[rr] = fmaf(x4.x, wk4.x, fmaf(x4.y, wk4.y, fmaf(x4.z, wk4.z, fmaf(x4.w, wk4.w, ak[rr]))));
        av[rr] = fmaf(x4.x, wv4.x, fmaf(x4.y, wv4.y, fmaf(x4.z, wv4.z, fmaf(x4.w, wv4.w, av[rr]))));
      }
    }
    for (int rr = 0; rr < 7; rr++) {
      if (rr < cnt) {
        ws[WS_KH + (unsigned)(r0 + rr) * 256u + t] = ak[rr];
        ws[WS_VH + (unsigned)(r0 + rr) * 256u + t] = av[rr];
      }
    }
  }
}

// ---------------------------------------------------------------------------
// bias kernel v3 (transposed): per block = 8 queries, 512 threads (8 waves).
// GEMM1: D1[c][key] = sum_k W1[c][k] * pe[key][k]  (A=W1 in regs, B=pe via LDS)
// wave w owns ctiles {2w,2w+1} (c in [32w,32w+32)), all 7 key-mtiles.
// GEMM2: per mtile, tiny LDS exchange -> wave mt does full K=256 contraction.
// LDS: peA dbuf [2][896 frags]@0 (28672) + qe bf16[8][256]@28672 (4096)
//      + region dbuf [2][8192]@32768 (16384) = 49152 B
__global__ __launch_bounds__(512) void bias_kernel(
    const float* __restrict__ qpos,
    const float* __restrict__ pos_b1, const float* __restrict__ pos_b2,
    float* __restrict__ ws)
{
  __shared__ __align__(16) char smem[49152];
  __bf16* qe_s = (__bf16*)(smem + 28672);

  int bid = blockIdx.x;          // 0..399 -> q rows bid*8 .. bid*8+7
  int n = bid / 200;
  int q0 = bid * 8;
  int t = threadIdx.x;
  int lane = t & 63, w = t >> 6;
  int l15 = lane & 15, quad = lane >> 4;

  const __bf16* keb = (const __bf16*)(ws + WS_KEB) + (unsigned)(n * 100) * 264u;
  const __bf16* w1b = (const __bf16*)(ws + WS_W1B);
  const __bf16* w2pb = (const __bf16*)(ws + WS_W2PB);
  __bf16* biasb = (__bf16*)(ws + WS_BIASB);

  // qe table for the block's 8 queries (bf16), 4 values/thread
  {
    int idx = t * 4;
    int q = idx >> 8, u = idx & 255;
    float p0 = qpos[(q0 + q) * 2 + 0], p1 = qpos[(q0 + q) * 2 + 1];
    bf16x4 o;
#pragma unroll
    for (int j = 0; j < 4; j++) {
      int u2 = u + j;
      int c = u2 >> 7, i = (u2 & 127) >> 1;
      float p = c ? p1 : p0;
      float inv = exp2f((float)i * (-13.287712379549449f / 64.0f));
      float v = p * inv;
      o[j] = (__bf16)((u2 & 1) ? __cosf(v) : __sinf(v));
    }
    *(bf16x4*)(qe_s + idx) = o;
  }

  // W1 A-frags in registers: wave w, ctile ct, k-chunk kc (loaded once)
  bf16x8 wfrag[2][8];
#pragma unroll
  for (int ct = 0; ct < 2; ct++)
#pragma unroll
    for (int kc = 0; kc < 8; kc++)
      wfrag[ct][kc] = *(const bf16x8*)(w1b + (unsigned)(w * 32 + ct * 16 + l15) * 256u + kc * 32 + quad * 8);
  // per-lane bias values: c = 32w + ct*16 + quad*4 + r
  float b1v[2][4];
#pragma unroll
  for (int ct = 0; ct < 2; ct++)
#pragma unroll
    for (int r = 0; r < 4; r++) b1v[ct][r] = pos_b1[w * 32 + ct * 16 + quad * 4 + r];
  float b2v[4];
#pragma unroll
  for (int r = 0; r < 4; r++) b2v[r] = pos_b2[(quad * 4 + r) & 7];

  // pe generator: one kc-PAIR per call. thread t<448: key=t>>2, sub=t&3
  // covers 16 cols = cols pair*64 + sub*16 .. +15 -> 2 frags (quad qd0, qd0+1)
  auto gen = [&](int q, int pair, int buf) {
    if (t < 448) {
      int key = t >> 2, sub = t & 3;
      int cb = pair * 64 + sub * 16;
      bf16x8 fr0, fr1;
      const __bf16* qp = qe_s + q * 256 + cb;
      bf16x8 q0f = *(const bf16x8*)qp;
      bf16x8 q1f = *(const bf16x8*)(qp + 8);
      if (key < 100) {
        const __bf16* kp = keb + (unsigned)key * 264u + cb;
        bf16x8 k0f = *(const bf16x8*)kp;
        bf16x8 k1f = *(const bf16x8*)(kp + 8);
#pragma unroll
        for (int jj = 0; jj < 4; jj++) {
          float sk = (float)k0f[2 * jj], ck = (float)k0f[2 * jj + 1];
          float sq = (float)q0f[2 * jj], cq = (float)q0f[2 * jj + 1];
          fr0[2 * jj]     = (__bf16)(sk * cq - ck * sq);
          fr0[2 * jj + 1] = (__bf16)(ck * cq + sk * sq);
          float sk1 = (float)k1f[2 * jj], ck1 = (float)k1f[2 * jj + 1];
          float sq1 = (float)q1f[2 * jj], cq1 = (float)q1f[2 * jj + 1];
          fr1[2 * jj]     = (__bf16)(sk1 * cq1 - ck1 * sq1);
          fr1[2 * jj + 1] = (__bf16)(ck1 * cq1 + sk1 * sq1);
        }
      } else {
#pragma unroll
        for (int jj = 0; jj < 8; jj++) { fr0[jj] = (__bf16)0.f; fr1[jj] = (__bf16)0.f; }
      }
      int mt = key >> 4, kl = key & 15;
      int kcl = sub >> 1;           // kc within pair
      int qd0 = (sub & 1) * 2;
      bf16x8* dst = (bf16x8*)smem + buf * 896 + kcl * 448 + mt * 64 + qd0 * 16 + kl;
      dst[0] = fr0;
      dst[16] = fr1;
    }
  };

  f32x4 zero4; zero4[0] = 0.f; zero4[1] = 0.f; zero4[2] = 0.f; zero4[3] = 0.f;

  __syncthreads();           // qe_s ready
  gen(0, 0, 0);
  __syncthreads();

  for (int q = 0; q < 8; q++) {
    f32x4 acc[2][7];
#pragma unroll
    for (int ct = 0; ct < 2; ct++)
#pragma unroll
      for (int mt = 0; mt < 7; mt++) acc[ct][mt] = zero4;

    for (int p = 0; p < 4; p++) {
      // prefetch next pe buffer (or next query's first)
      if (p < 3) gen(q, p + 1, (p + 1) & 1);
      else if (q < 7) gen(q + 1, 0, 0);
      const bf16x8* pb = (const bf16x8*)smem + (p & 1) * 896;
#pragma unroll
      for (int kh = 0; kh < 2; kh++) {
        int kc = p * 2 + kh;
        bf16x8 pf[7];
#pragma unroll
        for (int mt = 0; mt < 7; mt++) pf[mt] = pb[kh * 448 + mt * 64 + lane];
#pragma unroll
        for (int mt = 0; mt < 7; mt++) {
          acc[0][mt] = __builtin_amdgcn_mfma_f32_16x16x32_bf16(wfrag[0][kc], pf[mt], acc[0][mt], 0, 0, 0);
          acc[1][mt] = __builtin_amdgcn_mfma_f32_16x16x32_bf16(wfrag[1][kc], pf[mt], acc[1][mt], 0, 0, 0);
        }
      }
      __syncthreads();
    }

    // hid = relu(D1 + b1), in place (lane holds hid[c=32w+ct*16+quad*4+r][key=mt*16+l15])
#pragma unroll
    for (int ct = 0; ct < 2; ct++)
#pragma unroll
      for (int mt = 0; mt < 7; mt++)
#pragma unroll
        for (int r = 0; r < 4; r++)
          acc[ct][mt][r] = fmaxf(acc[ct][mt][r] + b1v[ct][r], 0.0f);

    // GEMM2: per mtile exchange into 8KB region (dbuf), wave mt contracts K=256
    __bf16* region = (__bf16*)(smem + 32768);
    auto wreg = [&](int mt, int rb) {
#pragma unroll
      for (int ct = 0; ct < 2; ct++) {
        int qt = ct * 2 + (quad >> 1);
        int j0 = (quad & 1) * 4;
        bf16x4 o;
#pragma unroll
        for (int r = 0; r < 4; r++) o[r] = (__bf16)acc[ct][mt][r];
        *(bf16x4*)(region + rb * 4096 + ((w * 64 + qt * 16 + l15) << 3) + j0) = o;
      }
    };
    wreg(0, 0);
    __syncthreads();
    for (int mt = 0; mt < 7; mt++) {
      if (w == mt) {
        f32x4 acc2 = zero4;
        const bf16x8* rg = (const bf16x8*)region + (mt & 1) * 512;
#pragma unroll
        for (int s = 0; s < 8; s++) {
          bf16x8 w2f = *(const bf16x8*)(w2pb + (unsigned)l15 * 256u + s * 32 + quad * 8);
          bf16x8 hf = rg[s * 64 + lane];
          acc2 = __builtin_amdgcn_mfma_f32_16x16x32_bf16(w2f, hf, acc2, 0, 0, 0);
        }
        if (quad < 2) {
          bf16x4 o;
#pragma unroll
          for (int r = 0; r < 4; r++) o[r] = (__bf16)(acc2[r] + b2v[r]);
          *(bf16x4*)(biasb + ((unsigned)(q0 + q) * 112u + mt * 16 + l15) * 8u + quad * 4) = o;
        }
      }
      if (mt < 6) wreg(mt + 1, (mt + 1) & 1);
      __syncthreads();
    }
  }
}

// ---------------------------------------------------------------------------
// attn kernel: per block = 4 queries. scores -> softmax -> ctx/aw -> out_proj
// -> cat_pos -> embed. 256 threads.
__global__ __launch_bounds__(256, 4) void attn_kernel(
    const float* __restrict__ qfeat, const float* __restrict__ qpos,
    const float* __restrict__ kpos,
    const float* __restrict__ out_w, const float* __restrict__ out_b,
    const float* __restrict__ embed_b, const float* __restrict__ ptw,
    const float* __restrict__ ws, float* __restrict__ out)
{
  __shared__ float qh_s[4 * 8 * 36];     // [q][h][36] padded
  __shared__ float attn_s[4 * 8 * 116];  // [q][h][116] padded
  __shared__ float ctx_s[4 * 264];
  __shared__ float cat_s[4 * 264];
  __shared__ float aw_s[4 * 104];

  int bid = blockIdx.x;
  int qg0 = bid * 4;
  int n = bid / 400;
  int t = threadIdx.x;

  const __bf16* qhb = (const __bf16*)(ws + WS_QHB);
  const __bf16* biasb = (const __bf16*)(ws + WS_BIASB);
  const float* kh = ws + WS_KH;
  const float* vh = ws + WS_VH;
  const float* ewp = ws + WS_EWP;

  for (int i = t; i < 1024; i += 256) {
    int q = i >> 8, c = i & 255;
    qh_s[(q * 8 + (c >> 5)) * 36 + (c & 31)] = (float)qhb[(unsigned)(qg0 + q) * 256u + c];
  }
  __syncthreads();

  // scores = qh.kh + bias  -> attn_s[q][h][k]
  for (int i = 0; i < 4; i++) {
    int p = t + i * 256;
    if (p < 800) {
      int k = p >> 3, h = p & 7;
      const float4* kf = (const float4*)(kh + (unsigned)(n * 100 + k) * 256u + h * 32);
      float4 kv[8];
#pragma unroll
      for (int dd = 0; dd < 8; dd++) kv[dd] = kf[dd];
#pragma unroll
      for (int q = 0; q < 4; q++) {
        const float4* qf = (const float4*)(qh_s + (q * 8 + h) * 36);
        float s = (float)biasb[((unsigned)(qg0 + q) * 112u + k) * 8u + h];
#pragma unroll
        for (int dd = 0; dd < 8; dd++) {
          float4 qv = qf[dd];
          s += kv[dd].x * qv.x + kv[dd].y * qv.y + kv[dd].z * qv.z + kv[dd].w * qv.w;
        }
        attn_s[(q * 8 + h) * 116 + k] = s;
      }
    }
  }
  __syncthreads();

  // softmax: 256 threads = 4q x 8h x 8 lanes-per-row
  {
    int q = t >> 6, h = (t >> 3) & 7, j = t & 7;
    float* row = attn_s + (q * 8 + h) * 116;
    float mx = -1e30f;
    for (int k = j; k < 100; k += 8) mx = fmaxf(mx, row[k]);
    mx = fmaxf(mx, __shfl_xor(mx, 1, 8));
    mx = fmaxf(mx, __shfl_xor(mx, 2, 8));
    mx = fmaxf(mx, __shfl_xor(mx, 4, 8));
    float sum = 0.f;
    for (int k = j; k < 100; k += 8) { float e = __expf(row[k] - mx); row[k] = e; sum += e; }
    sum += __shfl_xor(sum, 1, 8);
    sum += __shfl_xor(sum, 2, 8);
    sum += __shfl_xor(sum, 4, 8);
    float inv = 1.0f / sum;
    for (int k = j; k < 100; k += 8) row[k] *= inv;
  }
  __syncthreads();

  // aw = mean over heads
  for (int p = t; p < 416; p += 256) {
    int q = p / 104, k = p % 104;
    if (k < 100) {
      float s = 0.f;
#pragma unroll
      for (int h = 0; h < 8; h++) s += attn_s[(q * 8 + h) * 116 + k];
      aw_s[q * 104 + k] = s * 0.125f;
    }
  }
  // ctx[q][c] = sum_k attn[q][h(c)][k] * vh[k][c]
  {
    int c = t, h = c >> 5;
    float a0 = 0.f, a1 = 0.f, a2 = 0.f, a3 = 0.f;
    const float* vp = vh + (unsigned)(n * 100) * 256u + c;
    const float* r0 = attn_s + (0 * 8 + h) * 116;
    const float* r1 = attn_s + (1 * 8 + h) * 116;
    const float* r2 = attn_s + (2 * 8 + h) * 116;
    const float* r3 = attn_s + (3 * 8 + h) * 116;
#pragma unroll 4
    for (int k = 0; k < 100; k++) {
      float vv = vp[(unsigned)k * 256u];
      a0 = fmaf(r0[k], vv, a0);
      a1 = fmaf(r1[k], vv, a1);
      a2 = fmaf(r2[k], vv, a2);
      a3 = fmaf(r3[k], vv, a3);
    }
    ctx_s[0 * 264 + c] = a0; ctx_s[1 * 264 + c] = a1;
    ctx_s[2 * 264 + c] = a2; ctx_s[3 * 264 + c] = a3;
  }
  __syncthreads();

  // new_rel -> new_pos (cat extras)
  if (t < 8) {
    int q = t >> 1, cd = t & 1;
    float qp = qpos[(qg0 + q) * 2 + cd];
    float s = 0.f;
    for (int k = 0; k < 100; k++)
      s = fmaf(aw_s[q * 104 + k], kpos[(n * 100 + k) * 2 + cd] - qp, s);
    float so = __shfl_xor(s, 1, 2);
    if (cd == 0) cat_s[q * 264 + 256] = ptw[0] * s + ptw[1] * so;
    else         cat_s[q * 264 + 257] = ptw[2] * so + ptw[3] * s;
  }

  // out_proj: thread c owns out_w row c; ctx broadcast via readlane
  {
    int c = t, lane = t & 63;
    float ob = out_b[c];
    float acc0 = ob, acc1 = ob, acc2 = ob, acc3 = ob;
    const float* wr = out_w + (unsigned)c * 256u;
    for (int ch = 0; ch < 4; ch++) {
      float v0 = ctx_s[0 * 264 + ch * 64 + lane];
      float v1 = ctx_s[1 * 264 + ch * 64 + lane];
      float v2 = ctx_s[2 * 264 + ch * 64 + lane];
      float v3 = ctx_s[3 * 264 + ch * 64 + lane];
      const float* wp = wr + ch * 64;
#pragma unroll 4
      for (int j4 = 0; j4 < 16; j4++) {
        float4 w4 = *(const float4*)(wp + j4 * 4);
        int jb = j4 * 4;
        acc0 = fmaf(rdlane(v0, jb + 0), w4.x, acc0);
        acc1 = fmaf(rdlane(v1, jb + 0), w4.x, acc1);
        acc2 = fmaf(rdlane(v2, jb + 0), w4.x, acc2);
        acc3 = fmaf(rdlane(v3, jb + 0), w4.x, acc3);
        acc0 = fmaf(rdlane(v0, jb + 1), w4.y, acc0);
        acc1 = fmaf(rdlane(v1, jb + 1), w4.y, acc1);
        acc2 = fmaf(rdlane(v2, jb + 1), w4.y, acc2);
        acc3 = fmaf(rdlane(v3, jb + 1), w4.y, acc3);
        acc0 = fmaf(rdlane(v0, jb + 2), w4.z, acc0);
        acc1 = fmaf(rdlane(v1, jb + 2), w4.z, acc1);
        acc2 = fmaf(rdlane(v2, jb + 2), w4.z, acc2);
        acc3 = fmaf(rdlane(v3, jb + 2), w4.z, acc3);
        acc0 = fmaf(rdlane(v0, jb + 3), w4.w, acc0);
        acc1 = fmaf(rdlane(v1, jb + 3), w4.w, acc1);
        acc2 = fmaf(rdlane(v2, jb + 3), w4.w, acc2);
        acc3 = fmaf(rdlane(v3, jb + 3), w4.w, acc3);
      }
    }
    cat_s[0 * 264 + c] = fmaxf(qfeat[(unsigned)(qg0 + 0) * 256u + c] + acc0, 0.f);
    cat_s[1 * 264 + c] = fmaxf(qfeat[(unsigned)(qg0 + 1) * 256u + c] + acc1, 0.f);
    cat_s[2 * 264 + c] = fmaxf(qfeat[(unsigned)(qg0 + 2) * 256u + c] + acc2, 0.f);
    cat_s[3 * 264 + c] = fmaxf(qfeat[(unsigned)(qg0 + 3) * 256u + c] + acc3, 0.f);
  }
  __syncthreads();

  // embed: thread c owns ewp row c (stride 260, cols 256/257 = new_pos)
  {
    int c = t, lane = t & 63;
    float eb = embed_b[c];
    float acc0 = eb, acc1 = eb, acc2 = eb, acc3 = eb;
    const float* er = ewp + (unsigned)c * 260u;
    for (int ch = 0; ch < 4; ch++) {
      float v0 = cat_s[0 * 264 + ch * 64 + lane];
      float v1 = cat_s[1 * 264 + ch * 64 + lane];
      float v2 = cat_s[2 * 264 + ch * 64 + lane];
      float v3 = cat_s[3 * 264 + ch * 64 + lane];
      const float* wp = er + ch * 64;
#pragma unroll 4
      for (int j4 = 0; j4 < 16; j4++) {
        float4 w4 = *(const float4*)(wp + j4 * 4);
        int jb = j4 * 4;
        acc0 = fmaf(rdlane(v0, jb + 0), w4.x, acc0);
        acc1 = fmaf(rdlane(v1, jb + 0), w4.x, acc1);
        acc2 = fmaf(rdlane(v2, jb + 0), w4.x, acc2);
        acc3 = fmaf(rdlane(v3, jb + 0), w4.x, acc3);
        acc0 = fmaf(rdlane(v0, jb + 1), w4.y, acc0);
        acc1 = fmaf(rdlane(v1, jb + 1), w4.y, acc1);
        acc2 = fmaf(rdlane(v2, jb + 1), w4.y, acc2);
        acc3 = fmaf(rdlane(v3, jb + 1), w4.y, acc3);
        acc0 = fmaf(rdlane(v0, jb + 2), w4.z, acc0);
        acc1 = fmaf(rdlane(v1, jb + 2), w4.z, acc1);
        acc2 = fmaf(rdlane(v2, jb + 2), w4.z, acc2);
        acc3 = fmaf(rdlane(v3, jb + 2), w4.z, acc3);
        acc0 = fmaf(rdlane(v0, jb + 3), w4.w, acc0);
        acc1 = fmaf(rdlane(v1, jb + 3), w4.w, acc1);
        acc2 = fmaf(rdlane(v2, jb + 3), w4.w, acc2);
        acc3 = fmaf(rdlane(v3, jb + 3), w4.w, acc3);
      }
    }
    float4 wt = *(const float4*)(er + 256);
    acc0 += cat_s[0 * 264 + 256] * wt.x + cat_s[0 * 264 + 257] * wt.y;
    acc1 += cat_s[1 * 264 + 256] * wt.x + cat_s[1 * 264 + 257] * wt.y;
    acc2 += cat_s[2 * 264 + 256] * wt.x + cat_s[2 * 264 + 257] * wt.y;
    acc3 += cat_s[3 * 264 + 256] * wt.x + cat_s[3 * 264 + 257] * wt.y;
    out[(unsigned)(qg0 + 0) * 256u + c] = fmaxf(acc0, 0.f);
    out[(unsigned)(qg0 + 1) * 256u + c] = fmaxf(acc1, 0.f);
    out[(unsigned)(qg0 + 2) * 256u + c] = fmaxf(acc2, 0.f);
    out[(unsigned)(qg0 + 3) * 256u + c] = fmaxf(acc3, 0.f);
  }
}

// ---------------------------------------------------------------------------
extern "C" void kernel_launch(void* const* d_in, const int* in_sizes, int n_in,
                              void* d_out, int out_size, void* d_ws, size_t ws_size,
                              hipStream_t stream)
{
  const float* query_feature  = (const float*)d_in[0];
  const float* query_position = (const float*)d_in[1];
  const float* key_feature    = (const float*)d_in[2];
  const float* key_position   = (const float*)d_in[3];
  const float* in_proj_w      = (const float*)d_in[4];
  const float* in_proj_b      = (const float*)d_in[5];
  const float* out_proj_w     = (const float*)d_in[6];
  const float* out_proj_b     = (const float*)d_in[7];
  const float* pos_w1         = (const float*)d_in[8];
  const float* pos_b1         = (const float*)d_in[9];
  const float* pos_w2         = (const float*)d_in[10];
  const float* pos_b2         = (const float*)d_in[11];
  const float* pos_trans_w    = (const float*)d_in[12];
  const float* embed_w        = (const float*)d_in[13];
  const float* embed_b        = (const float*)d_in[14];
  float* ws  = (float*)d_ws;
  float* out = (float*)d_out;

  hipLaunchKernelGGL(prep_kernel, dim3(579), dim3(256), 0, stream,
                     query_feature, key_feature, key_position,
                     in_proj_w, in_proj_b, pos_w1, pos_w2, embed_w, ws);
  hipLaunchKernelGGL(bias_kernel, dim3(400), dim3(512), 0, stream,
                     query_position, pos_b1, pos_b2, ws);
  hipLaunchKernelGGL(attn_kernel, dim3(800), dim3(256), 0, stream,
                     query_feature, query_position, key_position,
                     out_proj_w, out_proj_b, embed_b, pos_trans_w,
                     ws, out);
}

// Round 5
// 295.135 us; speedup vs baseline: 1.5288x; 1.0210x over previous
//
#include <hip/hip_runtime.h>
#include <math.h>

typedef __bf16 bf16x8 __attribute__((ext_vector_type(8)));
typedef __bf16 bf16x4 __attribute__((ext_vector_type(4)));
typedef float  f32x4  __attribute__((ext_vector_type(4)));

// N=2, Q=1600, K=100 (pad 112), C=256, h=8, d=32.
// bias: transposed MFMA GEMM, Qb=4/block, grid 800. attn: Qb=4/block.

// ---- workspace layout (float offsets), total 2,073,376 f32 = 8.29 MB ----
#define WS_KH    0u        // [200][256] f32 k projection                 -> 51200
#define WS_VH    51200u    // [200][256] f32 v projection                 -> 102400
#define WS_EWP   102400u   // [256][260] f32 embed_w padded rows          -> 168960
#define WS_QHB   168960u   // bf16 [3200][256] scaled q projection        -> 578560
#define WS_BIASB 578560u   // bf16 [3200][112][8] rel-pos bias            -> 2012160
#define WS_KEB   2012160u  // bf16 [200][264] key sin/cos table (pad 264) -> 2038560
#define WS_W1B   2038560u  // bf16 [256][256] pos_w1                      -> 2071328
#define WS_W2PB  2071328u  // bf16 [16][256] pos_w2 padded                -> 2073376

__device__ __forceinline__ float rdlane(float v, int l) {
  return __uint_as_float(__builtin_amdgcn_readlane(__float_as_uint(v), l));
}

// ---------------------------------------------------------------------------
// prep: keb table + bf16 casts + embed_w pad + q/k/v projections (fused)
__global__ __launch_bounds__(256, 2) void prep_kernel(
    const float* __restrict__ qfeat, const float* __restrict__ kfeat,
    const float* __restrict__ kpos,
    const float* __restrict__ ipw, const float* __restrict__ ipb,
    const float* __restrict__ pos_w1, const float* __restrict__ pos_w2,
    const float* __restrict__ embed_w, float* __restrict__ ws)
{
  __shared__ float x[8 * 256];
  int bid = blockIdx.x, t = threadIdx.x;

  if (bid < 50) {
    int r = bid * 4 + (t >> 6);
    int u = t & 63;
    float p0 = kpos[r * 2 + 0], p1 = kpos[r * 2 + 1];
    __bf16* keb = (__bf16*)(ws + WS_KEB);
    bf16x4 o;
#pragma unroll
    for (int j = 0; j < 4; j++) {
      int col = u * 4 + j;
      int c = col >> 7, i = (col & 127) >> 1;
      float p = c ? p1 : p0;
      float inv = exp2f((float)i * (-13.287712379549449f / 64.0f));
      float v = p * inv;
      o[j] = (__bf16)((col & 1) ? __cosf(v) : __sinf(v));
    }
    *(bf16x4*)(keb + r * 264 + u * 4) = o;
  } else if (bid < 114) {
    int idx = (bid - 50) * 1024 + t * 4;
    float4 v = *(const float4*)(pos_w1 + idx);
    bf16x4 o; o[0] = (__bf16)v.x; o[1] = (__bf16)v.y; o[2] = (__bf16)v.z; o[3] = (__bf16)v.w;
    *(bf16x4*)((__bf16*)(ws + WS_W1B) + idx) = o;
  } else if (bid == 114) {
    __bf16* w2pb = (__bf16*)(ws + WS_W2PB);
    for (int i = 0; i < 16; i++) {
      int idx = t * 16 + i;
      w2pb[idx] = (idx < 2048) ? (__bf16)pos_w2[idx] : (__bf16)0.0f;
    }
  } else if (bid < 147) {
    int r0 = (bid - 115) * 8;
    for (int rr = 0; rr < 8; rr++) {
      int r = r0 + rr;
      for (int j = t; j < 260; j += 256)
        ws[WS_EWP + r * 260 + j] = (j < 258) ? embed_w[r * 258 + j] : 0.0f;
    }
  } else if (bid < 547) {
    int r0 = (bid - 147) * 8;
    for (int i = t; i < 2048; i += 256) x[i] = qfeat[(unsigned)r0 * 256u + i];
    __syncthreads();
    float acc[8]; float bq = ipb[t];
#pragma unroll
    for (int rr = 0; rr < 8; rr++) acc[rr] = bq;
    const float* wrow = ipw + (unsigned)t * 256u;
    for (int j = 0; j < 256; j += 4) {
      float4 w4 = *(const float4*)(wrow + j);
#pragma unroll
      for (int rr = 0; rr < 8; rr++) {
        float4 x4 = *(const float4*)(x + rr * 256 + j);
        acc[rr] = fmaf(x4.x, w4.x, fmaf(x4.y, w4.y, fmaf(x4.z, w4.z, fmaf(x4.w, w4.w, acc[rr]))));
      }
    }
    __bf16* qhb = (__bf16*)(ws + WS_QHB);
#pragma unroll
    for (int rr = 0; rr < 8; rr++)
      qhb[(unsigned)(r0 + rr) * 256u + t] = (__bf16)(acc[rr] * 0.17677669529663687f);
  } else {
    int b2 = bid - 547; int n = b2 >> 4, tile = b2 & 15;
    int r0l = tile * 7; int cnt = 100 - r0l; if (cnt > 7) cnt = 7; if (cnt <= 0) return;
    int r0 = n * 100 + r0l;
    for (int i = t; i < cnt * 256; i += 256) x[i] = kfeat[(unsigned)r0 * 256u + i];
    __syncthreads();
    float ak[7], av[7]; float bk = ipb[256 + t], bv = ipb[512 + t];
#pragma unroll
    for (int rr = 0; rr < 7; rr++) { ak[rr] = bk; av[rr] = bv; }
    const float* wkr = ipw + (unsigned)(256 + t) * 256u;
    const float* wvr = ipw + (unsigned)(512 + t) * 256u;
    for (int j = 0; j < 256; j += 4) {
      float4 wk4 = *(const float4*)(wkr + j);
      float4 wv4 = *(const float4*)(wvr + j);
#pragma unroll
      for (int rr = 0; rr < 7; rr++) {
        float4 x4 = *(const float4*)(x + rr * 256 + j);
        ak[rr] = fmaf(x4.x, wk4.x, fmaf(x4.y, wk4.y, fmaf(x4.z, wk4.z, fmaf(x4.w, wk4.w, ak[rr]))));
        av[rr] = fmaf(x4.x, wv4.x, fmaf(x4.y, wv4.y, fmaf(x4.z, wv4.z, fmaf(x4.w, wv4.w, av[rr]))));
      }
    }
    for (int rr = 0; rr < 7; rr++) {
      if (rr < cnt) {
        ws[WS_KH + (unsigned)(r0 + rr) * 256u + t] = ak[rr];
        ws[WS_VH + (unsigned)(r0 + rr) * 256u + t] = av[rr];
      }
    }
  }
}

// ---------------------------------------------------------------------------
// bias kernel v4: per block = 4 queries, 512 threads (8 waves), grid 800.
// GEMM1: D1[c][key] = sum_k W1[c][k]*pe[key][k]; A=W1 in regs, B=pe via LDS
// (XOR bank-swizzled). GEMM2: parallel across waves, 2 batches (mt 0-3, 4-6).
// LDS: peA dbuf [2][896 frags]@0 (28672) + qe bf16[4][256]@28672 (2048)
//      + region 4 slots x 8192B @30720 (32768) = 63488 B
__global__ __launch_bounds__(512) void bias_kernel(
    const float* __restrict__ qpos,
    const float* __restrict__ pos_b1, const float* __restrict__ pos_b2,
    float* __restrict__ ws)
{
  __shared__ __align__(16) char smem[63488];
  __bf16* qe_s   = (__bf16*)(smem + 28672);
  __bf16* region = (__bf16*)(smem + 30720);

  int bid = blockIdx.x;          // 0..799 -> q rows bid*4 .. bid*4+3
  int n = bid / 400;
  int q0 = bid * 4;
  int t = threadIdx.x;
  int lane = t & 63, w = t >> 6;
  int l15 = lane & 15, quad = lane >> 4;

  const __bf16* keb = (const __bf16*)(ws + WS_KEB) + (unsigned)(n * 100) * 264u;
  const __bf16* w1b = (const __bf16*)(ws + WS_W1B);
  const __bf16* w2pb = (const __bf16*)(ws + WS_W2PB);
  __bf16* biasb = (__bf16*)(ws + WS_BIASB);

  // qe for the block's 4 queries: thread computes one sin/cos pair
  {
    int idx = t * 2;
    int q = idx >> 8, u = idx & 255;
    int c = u >> 7, i = (u & 127) >> 1;
    float p = qpos[(q0 + q) * 2 + c];
    float inv = exp2f((float)i * (-13.287712379549449f / 64.0f));
    float v = p * inv;
    qe_s[idx]     = (__bf16)__sinf(v);
    qe_s[idx + 1] = (__bf16)__cosf(v);
  }

  // W1 A-frags in registers: wave w owns c in [32w, 32w+32)
  bf16x8 wfrag[2][8];
#pragma unroll
  for (int ct = 0; ct < 2; ct++)
#pragma unroll
    for (int kc = 0; kc < 8; kc++)
      wfrag[ct][kc] = *(const bf16x8*)(w1b + (unsigned)(w * 32 + ct * 16 + l15) * 256u + kc * 32 + quad * 8);
  float b1v[2][4];
#pragma unroll
  for (int ct = 0; ct < 2; ct++)
#pragma unroll
    for (int r = 0; r < 4; r++) b1v[ct][r] = pos_b1[w * 32 + ct * 16 + quad * 4 + r];
  float b2v[4];
#pragma unroll
  for (int r = 0; r < 4; r++) b2v[r] = pos_b2[(quad * 4 + r) & 7];

  // pe generator: one kc-PAIR per call, XOR bank-swizzle on low 4 idx bits.
  auto gen = [&](int q, int pair, int buf) {
    if (t < 448) {
      int key = t >> 2, sub = t & 3;
      int cb = pair * 64 + sub * 16;
      bf16x8 fr0, fr1;
      const __bf16* qp = qe_s + q * 256 + cb;
      bf16x8 q0f = *(const bf16x8*)qp;
      bf16x8 q1f = *(const bf16x8*)(qp + 8);
      if (key < 100) {
        const __bf16* kp = keb + (unsigned)key * 264u + cb;
        bf16x8 k0f = *(const bf16x8*)kp;
        bf16x8 k1f = *(const bf16x8*)(kp + 8);
#pragma unroll
        for (int jj = 0; jj < 4; jj++) {
          float sk = (float)k0f[2 * jj], ck = (float)k0f[2 * jj + 1];
          float sq = (float)q0f[2 * jj], cq = (float)q0f[2 * jj + 1];
          fr0[2 * jj]     = (__bf16)(sk * cq - ck * sq);
          fr0[2 * jj + 1] = (__bf16)(ck * cq + sk * sq);
          float sk1 = (float)k1f[2 * jj], ck1 = (float)k1f[2 * jj + 1];
          float sq1 = (float)q1f[2 * jj], cq1 = (float)q1f[2 * jj + 1];
          fr1[2 * jj]     = (__bf16)(sk1 * cq1 - ck1 * sq1);
          fr1[2 * jj + 1] = (__bf16)(ck1 * cq1 + sk1 * sq1);
        }
      } else {
#pragma unroll
        for (int jj = 0; jj < 8; jj++) { fr0[jj] = (__bf16)0.f; fr1[jj] = (__bf16)0.f; }
      }
      int mt = key >> 4, kl = key & 15;
      int kcl = sub >> 1;
      int qd0 = (sub & 1) * 2;
      bf16x8* base = (bf16x8*)smem + buf * 896 + kcl * 448 + mt * 64;
      base[qd0 * 16 + (kl ^ (qd0 * 2 + kcl))]             = fr0;
      base[(qd0 + 1) * 16 + (kl ^ (qd0 * 2 + 2 + kcl))]   = fr1;
    }
  };

  f32x4 zero4; zero4[0] = 0.f; zero4[1] = 0.f; zero4[2] = 0.f; zero4[3] = 0.f;

  __syncthreads();           // qe_s ready
  gen(0, 0, 0);
  __syncthreads();

  for (int q = 0; q < 4; q++) {
    f32x4 acc[2][7];
#pragma unroll
    for (int ct = 0; ct < 2; ct++)
#pragma unroll
      for (int mt = 0; mt < 7; mt++) acc[ct][mt] = zero4;

    for (int p = 0; p < 4; p++) {
      if (p < 3) gen(q, p + 1, (p + 1) & 1);
      else if (q < 3) gen(q + 1, 0, 0);
      const bf16x8* pb = (const bf16x8*)smem + (p & 1) * 896;
#pragma unroll
      for (int kh = 0; kh < 2; kh++) {
        int kc = p * 2 + kh;
        bf16x8 pf[7];
#pragma unroll
        for (int mt = 0; mt < 7; mt++)
          pf[mt] = pb[kh * 448 + mt * 64 + quad * 16 + (l15 ^ (quad * 2 + kh))];
#pragma unroll
        for (int mt = 0; mt < 7; mt++) {
          acc[0][mt] = __builtin_amdgcn_mfma_f32_16x16x32_bf16(wfrag[0][kc], pf[mt], acc[0][mt], 0, 0, 0);
          acc[1][mt] = __builtin_amdgcn_mfma_f32_16x16x32_bf16(wfrag[1][kc], pf[mt], acc[1][mt], 0, 0, 0);
        }
      }
      __syncthreads();
    }

    // hid = relu(D1 + b1) in regs (lane: c=32w+ct*16+quad*4+r, key=mt*16+l15)
#pragma unroll
    for (int ct = 0; ct < 2; ct++)
#pragma unroll
      for (int mt = 0; mt < 7; mt++)
#pragma unroll
        for (int r = 0; r < 4; r++)
          acc[ct][mt][r] = fmaxf(acc[ct][mt][r] + b1v[ct][r], 0.0f);

    // GEMM2 exchange helpers
    auto wreg = [&](int mt, int slot) {
#pragma unroll
      for (int ct = 0; ct < 2; ct++) {
        int qt = ct * 2 + (quad >> 1);
        int j0 = (quad & 1) * 4;
        bf16x4 o;
#pragma unroll
        for (int r = 0; r < 4; r++) o[r] = (__bf16)acc[ct][mt][r];
        *(bf16x4*)(region + slot * 4096 + ((w * 64 + qt * 16 + l15) << 3) + j0) = o;
      }
    };
    auto g2 = [&](int mt, int slot) {
      f32x4 acc2 = zero4;
      const bf16x8* rg = (const bf16x8*)(region + slot * 4096);
#pragma unroll
      for (int s = 0; s < 8; s++) {
        bf16x8 w2f = *(const bf16x8*)(w2pb + (unsigned)l15 * 256u + s * 32 + quad * 8);
        bf16x8 hf = rg[s * 64 + lane];
        acc2 = __builtin_amdgcn_mfma_f32_16x16x32_bf16(w2f, hf, acc2, 0, 0, 0);
      }
      if (quad < 2) {
        bf16x4 o;
#pragma unroll
        for (int r = 0; r < 4; r++) o[r] = (__bf16)(acc2[r] + b2v[r]);
        *(bf16x4*)(biasb + ((unsigned)(q0 + q) * 112u + mt * 16 + l15) * 8u + quad * 4) = o;
      }
    };

    // batch 1: mtiles 0-3 in parallel
    wreg(0, 0); wreg(1, 1); wreg(2, 2); wreg(3, 3);
    __syncthreads();
    if (w < 4) g2(w, w);
    __syncthreads();
    // batch 2: mtiles 4-6
    wreg(4, 0); wreg(5, 1); wreg(6, 2);
    __syncthreads();
    if (w < 3) g2(4 + w, w);
    // next query's region writes are 4+ barriers away -> no extra sync needed
  }
}

// ---------------------------------------------------------------------------
// attn kernel: per block = 4 queries. scores -> softmax -> ctx/aw -> out_proj
// -> cat_pos -> embed. 256 threads.
__global__ __launch_bounds__(256, 4) void attn_kernel(
    const float* __restrict__ qfeat, const float* __restrict__ qpos,
    const float* __restrict__ kpos,
    const float* __restrict__ out_w, const float* __restrict__ out_b,
    const float* __restrict__ embed_b, const float* __restrict__ ptw,
    const float* __restrict__ ws, float* __restrict__ out)
{
  __shared__ float qh_s[4 * 8 * 36];
  __shared__ float attn_s[4 * 8 * 116];
  __shared__ float ctx_s[4 * 264];
  __shared__ float cat_s[4 * 264];
  __shared__ float aw_s[4 * 104];

  int bid = blockIdx.x;
  int qg0 = bid * 4;
  int n = bid / 400;
  int t = threadIdx.x;

  const __bf16* qhb = (const __bf16*)(ws + WS_QHB);
  const __bf16* biasb = (const __bf16*)(ws + WS_BIASB);
  const float* kh = ws + WS_KH;
  const float* vh = ws + WS_VH;
  const float* ewp = ws + WS_EWP;

  for (int i = t; i < 1024; i += 256) {
    int q = i >> 8, c = i & 255;
    qh_s[(q * 8 + (c >> 5)) * 36 + (c & 31)] = (float)qhb[(unsigned)(qg0 + q) * 256u + c];
  }
  __syncthreads();

  for (int i = 0; i < 4; i++) {
    int p = t + i * 256;
    if (p < 800) {
      int k = p >> 3, h = p & 7;
      const float4* kf = (const float4*)(kh + (unsigned)(n * 100 + k) * 256u + h * 32);
      float4 kv[8];
#pragma unroll
      for (int dd = 0; dd < 8; dd++) kv[dd] = kf[dd];
#pragma unroll
      for (int q = 0; q < 4; q++) {
        const float4* qf = (const float4*)(qh_s + (q * 8 + h) * 36);
        float s = (float)biasb[((unsigned)(qg0 + q) * 112u + k) * 8u + h];
#pragma unroll
        for (int dd = 0; dd < 8; dd++) {
          float4 qv = qf[dd];
          s += kv[dd].x * qv.x + kv[dd].y * qv.y + kv[dd].z * qv.z + kv[dd].w * qv.w;
        }
        attn_s[(q * 8 + h) * 116 + k] = s;
      }
    }
  }
  __syncthreads();

  {
    int q = t >> 6, h = (t >> 3) & 7, j = t & 7;
    float* row = attn_s + (q * 8 + h) * 116;
    float mx = -1e30f;
    for (int k = j; k < 100; k += 8) mx = fmaxf(mx, row[k]);
    mx = fmaxf(mx, __shfl_xor(mx, 1, 8));
    mx = fmaxf(mx, __shfl_xor(mx, 2, 8));
    mx = fmaxf(mx, __shfl_xor(mx, 4, 8));
    float sum = 0.f;
    for (int k = j; k < 100; k += 8) { float e = __expf(row[k] - mx); row[k] = e; sum += e; }
    sum += __shfl_xor(sum, 1, 8);
    sum += __shfl_xor(sum, 2, 8);
    sum += __shfl_xor(sum, 4, 8);
    float inv = 1.0f / sum;
    for (int k = j; k < 100; k += 8) row[k] *= inv;
  }
  __syncthreads();

  for (int p = t; p < 416; p += 256) {
    int q = p / 104, k = p % 104;
    if (k < 100) {
      float s = 0.f;
#pragma unroll
      for (int h = 0; h < 8; h++) s += attn_s[(q * 8 + h) * 116 + k];
      aw_s[q * 104 + k] = s * 0.125f;
    }
  }
  {
    int c = t, h = c >> 5;
    float a0 = 0.f, a1 = 0.f, a2 = 0.f, a3 = 0.f;
    const float* vp = vh + (unsigned)(n * 100) * 256u + c;
    const float* r0 = attn_s + (0 * 8 + h) * 116;
    const float* r1 = attn_s + (1 * 8 + h) * 116;
    const float* r2 = attn_s + (2 * 8 + h) * 116;
    const float* r3 = attn_s + (3 * 8 + h) * 116;
#pragma unroll 4
    for (int k = 0; k < 100; k++) {
      float vv = vp[(unsigned)k * 256u];
      a0 = fmaf(r0[k], vv, a0);
      a1 = fmaf(r1[k], vv, a1);
      a2 = fmaf(r2[k], vv, a2);
      a3 = fmaf(r3[k], vv, a3);
    }
    ctx_s[0 * 264 + c] = a0; ctx_s[1 * 264 + c] = a1;
    ctx_s[2 * 264 + c] = a2; ctx_s[3 * 264 + c] = a3;
  }
  __syncthreads();

  if (t < 8) {
    int q = t >> 1, cd = t & 1;
    float qp = qpos[(qg0 + q) * 2 + cd];
    float s = 0.f;
    for (int k = 0; k < 100; k++)
      s = fmaf(aw_s[q * 104 + k], kpos[(n * 100 + k) * 2 + cd] - qp, s);
    float so = __shfl_xor(s, 1, 2);
    if (cd == 0) cat_s[q * 264 + 256] = ptw[0] * s + ptw[1] * so;
    else         cat_s[q * 264 + 257] = ptw[2] * so + ptw[3] * s;
  }

  {
    int c = t, lane = t & 63;
    float ob = out_b[c];
    float acc0 = ob, acc1 = ob, acc2 = ob, acc3 = ob;
    const float* wr = out_w + (unsigned)c * 256u;
    for (int ch = 0; ch < 4; ch++) {
      float v0 = ctx_s[0 * 264 + ch * 64 + lane];
      float v1 = ctx_s[1 * 264 + ch * 64 + lane];
      float v2 = ctx_s[2 * 264 + ch * 64 + lane];
      float v3 = ctx_s[3 * 264 + ch * 64 + lane];
      const float* wp = wr + ch * 64;
#pragma unroll 4
      for (int j4 = 0; j4 < 16; j4++) {
        float4 w4 = *(const float4*)(wp + j4 * 4);
        int jb = j4 * 4;
        acc0 = fmaf(rdlane(v0, jb + 0), w4.x, acc0);
        acc1 = fmaf(rdlane(v1, jb + 0), w4.x, acc1);
        acc2 = fmaf(rdlane(v2, jb + 0), w4.x, acc2);
        acc3 = fmaf(rdlane(v3, jb + 0), w4.x, acc3);
        acc0 = fmaf(rdlane(v0, jb + 1), w4.y, acc0);
        acc1 = fmaf(rdlane(v1, jb + 1), w4.y, acc1);
        acc2 = fmaf(rdlane(v2, jb + 1), w4.y, acc2);
        acc3 = fmaf(rdlane(v3, jb + 1), w4.y, acc3);
        acc0 = fmaf(rdlane(v0, jb + 2), w4.z, acc0);
        acc1 = fmaf(rdlane(v1, jb + 2), w4.z, acc1);
        acc2 = fmaf(rdlane(v2, jb + 2), w4.z, acc2);
        acc3 = fmaf(rdlane(v3, jb + 2), w4.z, acc3);
        acc0 = fmaf(rdlane(v0, jb + 3), w4.w, acc0);
        acc1 = fmaf(rdlane(v1, jb + 3), w4.w, acc1);
        acc2 = fmaf(rdlane(v2, jb + 3), w4.w, acc2);
        acc3 = fmaf(rdlane(v3, jb + 3), w4.w, acc3);
      }
    }
    cat_s[0 * 264 + c] = fmaxf(qfeat[(unsigned)(qg0 + 0) * 256u + c] + acc0, 0.f);
    cat_s[1 * 264 + c] = fmaxf(qfeat[(unsigned)(qg0 + 1) * 256u + c] + acc1, 0.f);
    cat_s[2 * 264 + c] = fmaxf(qfeat[(unsigned)(qg0 + 2) * 256u + c] + acc2, 0.f);
    cat_s[3 * 264 + c] = fmaxf(qfeat[(unsigned)(qg0 + 3) * 256u + c] + acc3, 0.f);
  }
  __syncthreads();

  {
    int c = t, lane = t & 63;
    float eb = embed_b[c];
    float acc0 = eb, acc1 = eb, acc2 = eb, acc3 = eb;
    const float* er = ewp + (unsigned)c * 260u;
    for (int ch = 0; ch < 4; ch++) {
      float v0 = cat_s[0 * 264 + ch * 64 + lane];
      float v1 = cat_s[1 * 264 + ch * 64 + lane];
      float v2 = cat_s[2 * 264 + ch * 64 + lane];
      float v3 = cat_s[3 * 264 + ch * 64 + lane];
      const float* wp = er + ch * 64;
#pragma unroll 4
      for (int j4 = 0; j4 < 16; j4++) {
        float4 w4 = *(const float4*)(wp + j4 * 4);
        int jb = j4 * 4;
        acc0 = fmaf(rdlane(v0, jb + 0), w4.x, acc0);
        acc1 = fmaf(rdlane(v1, jb + 0), w4.x, acc1);
        acc2 = fmaf(rdlane(v2, jb + 0), w4.x, acc2);
        acc3 = fmaf(rdlane(v3, jb + 0), w4.x, acc3);
        acc0 = fmaf(rdlane(v0, jb + 1), w4.y, acc0);
        acc1 = fmaf(rdlane(v1, jb + 1), w4.y, acc1);
        acc2 = fmaf(rdlane(v2, jb + 1), w4.y, acc2);
        acc3 = fmaf(rdlane(v3, jb + 1), w4.y, acc3);
        acc0 = fmaf(rdlane(v0, jb + 2), w4.z, acc0);
        acc1 = fmaf(rdlane(v1, jb + 2), w4.z, acc1);
        acc2 = fmaf(rdlane(v2, jb + 2), w4.z, acc2);
        acc3 = fmaf(rdlane(v3, jb + 2), w4.z, acc3);
        acc0 = fmaf(rdlane(v0, jb + 3), w4.w, acc0);
        acc1 = fmaf(rdlane(v1, jb + 3), w4.w, acc1);
        acc2 = fmaf(rdlane(v2, jb + 3), w4.w, acc2);
        acc3 = fmaf(rdlane(v3, jb + 3), w4.w, acc3);
      }
    }
    float4 wt = *(const float4*)(er + 256);
    acc0 += cat_s[0 * 264 + 256] * wt.x + cat_s[0 * 264 + 257] * wt.y;
    acc1 += cat_s[1 * 264 + 256] * wt.x + cat_s[1 * 264 + 257] * wt.y;
    acc2 += cat_s[2 * 264 + 256] * wt.x + cat_s[2 * 264 + 257] * wt.y;
    acc3 += cat_s[3 * 264 + 256] * wt.x + cat_s[3 * 264 + 257] * wt.y;
    out[(unsigned)(qg0 + 0) * 256u + c] = fmaxf(acc0, 0.f);
    out[(unsigned)(qg0 + 1) * 256u + c] = fmaxf(acc1, 0.f);
    out[(unsigned)(qg0 + 2) * 256u + c] = fmaxf(acc2, 0.f);
    out[(unsigned)(qg0 + 3) * 256u + c] = fmaxf(acc3, 0.f);
  }
}

// ---------------------------------------------------------------------------
extern "C" void kernel_launch(void* const* d_in, const int* in_sizes, int n_in,
                              void* d_out, int out_size, void* d_ws, size_t ws_size,
                              hipStream_t stream)
{
  const float* query_feature  = (const float*)d_in[0];
  const float* query_position = (const float*)d_in[1];
  const float* key_feature    = (const float*)d_in[2];
  const float* key_position   = (const float*)d_in[3];
  const float* in_proj_w      = (const float*)d_in[4];
  const float* in_proj_b      = (const float*)d_in[5];
  const float* out_proj_w     = (const float*)d_in[6];
  const float* out_proj_b     = (const float*)d_in[7];
  const float* pos_w1         = (const float*)d_in[8];
  const float* pos_b1         = (const float*)d_in[9];
  const float* pos_w2         = (const float*)d_in[10];
  const float* pos_b2         = (const float*)d_in[11];
  const float* pos_trans_w    = (const float*)d_in[12];
  const float* embed_w        = (const float*)d_in[13];
  const float* embed_b        = (const float*)d_in[14];
  float* ws  = (float*)d_ws;
  float* out = (float*)d_out;

  hipLaunchKernelGGL(prep_kernel, dim3(579), dim3(256), 0, stream,
                     query_feature, key_feature, key_position,
                     in_proj_w, in_proj_b, pos_w1, pos_w2, embed_w, ws);
  hipLaunchKernelGGL(bias_kernel, dim3(800), dim3(512), 0, stream,
                     query_position, pos_b1, pos_b2, ws);
  hipLaunchKernelGGL(attn_kernel, dim3(800), dim3(256), 0, stream,
                     query_feature, query_position, key_position,
                     out_proj_w, out_proj_b, embed_b, pos_trans_w,
                     ws, out);
}